// Round 9
// baseline (279.041 us; speedup 1.0000x reference)
//
#include <hip/hip_runtime.h>

#define BATCH 2
#define S_LEN 2048
#define NH 12
#define DMODEL 768
// DK = 64, scale = 1/8

#define N8_BSD (BATCH * S_LEN * DMODEL / 8)  // 393216
#define N8_DD (DMODEL * DMODEL / 8)          // 73728

typedef __attribute__((ext_vector_type(8))) short bf16x8;
typedef __attribute__((ext_vector_type(4))) float f32x4;
typedef __attribute__((ext_vector_type(4))) unsigned short us4;

__device__ __forceinline__ unsigned short f2bf(float f) {
  union { float f; unsigned int u; } v; v.f = f;
  unsigned int r = v.u + 0x7fffu + ((v.u >> 16) & 1u);  // RNE
  return (unsigned short)(r >> 16);
}

// ------- f32 -> bf16 converts (8 elems/thread); cvt3 also zeroes ctx1 -------
__global__ void cvt3_kernel(const float* __restrict__ s0,
                            const float* __restrict__ s1,
                            const float* __restrict__ s2,
                            unsigned short* __restrict__ dst,
                            float* __restrict__ ctx1) {
  int i = blockIdx.x * blockDim.x + threadIdx.x;  // 0 .. 3*N8_BSD-1 (exact)
  int j = i / N8_BSD;
  int k = i - j * N8_BSD;
  const float* s = (j == 0) ? s0 : (j == 1) ? s1 : s2;
  const float4* sp = (const float4*)s;
  float4 a = sp[k * 2], b = sp[k * 2 + 1];
  us4 o0 = { f2bf(a.x), f2bf(a.y), f2bf(a.z), f2bf(a.w) };
  us4 o1 = { f2bf(b.x), f2bf(b.y), f2bf(b.z), f2bf(b.w) };
  us4* d = (us4*)dst;
  d[i * 2] = o0;
  d[i * 2 + 1] = o1;
  if (j == 0) {  // zero ctx1 partial buffer (BSD f32 = exactly this segment)
    f32x4 z = (f32x4){0.f, 0.f, 0.f, 0.f};
    f32x4* c = (f32x4*)ctx1;
    c[k * 2] = z;
    c[k * 2 + 1] = z;
  }
}

__global__ void cvt4_kernel(const float* __restrict__ s0,
                            const float* __restrict__ s1,
                            const float* __restrict__ s2,
                            const float* __restrict__ s3,
                            unsigned short* __restrict__ dst) {
  int i = blockIdx.x * blockDim.x + threadIdx.x;  // 0 .. 4*N8_DD-1 (exact)
  int j = i / N8_DD;
  int k = i - j * N8_DD;
  const float* s = (j == 0) ? s0 : (j == 1) ? s1 : (j == 2) ? s2 : s3;
  const float4* sp = (const float4*)s;
  float4 a = sp[k * 2], b = sp[k * 2 + 1];
  us4 o0 = { f2bf(a.x), f2bf(a.y), f2bf(a.z), f2bf(a.w) };
  us4 o1 = { f2bf(b.x), f2bf(b.y), f2bf(b.z), f2bf(b.w) };
  us4* d = (us4*)dst;
  d[i * 2] = o0;
  d[i * 2 + 1] = o1;
}

// ------- reduce: ctx_bf16 = f2bf(ctx0 + ctx1), 4 elems/thread -------
__global__ void ctx_reduce(const float* __restrict__ c0,
                           const float* __restrict__ c1,
                           unsigned short* __restrict__ o) {
  int i = blockIdx.x * blockDim.x + threadIdx.x;  // 0 .. BSD/4-1
  float4 a = ((const float4*)c0)[i];
  float4 b = ((const float4*)c1)[i];
  us4 r = { f2bf(a.x + b.x), f2bf(a.y + b.y), f2bf(a.z + b.z), f2bf(a.w + b.w) };
  ((us4*)o)[i] = r;
}

#define GLD_LDS16(g, l)                                                    \
  __builtin_amdgcn_global_load_lds(                                        \
      (const __attribute__((address_space(1))) unsigned int*)(g),          \
      (__attribute__((address_space(3))) unsigned int*)(l), 16, 0, 0)

// ---------------- fused QKV projection GEMM, 128x128 tile ----------------
__global__ __launch_bounds__(256, 2)
void gemm_qkv(const unsigned short* __restrict__ Aq,
              const unsigned short* __restrict__ Ak,
              const unsigned short* __restrict__ Av,
              const unsigned short* __restrict__ W3,
              unsigned short* __restrict__ Qs,
              unsigned short* __restrict__ Ks,
              unsigned short* __restrict__ VT) {
  __shared__ unsigned short As[128 * 64];
  __shared__ unsigned short Bs[128 * 64];
  const int m0 = blockIdx.x * 128;
  const int n0g = blockIdx.y * 128;
  const int nblk = n0g / 768;         // 0=Q 1=K 2=V (uniform per block)
  const int n0 = n0g - nblk * 768;
  const unsigned short* A = (nblk == 0) ? Aq : (nblk == 1) ? Ak : Av;
  const unsigned short* Bw = W3 + (size_t)n0g * DMODEL;
  const int tid = threadIdx.x, w = tid >> 6, l = tid & 63;
  const int lg = l >> 4, ll = l & 15;
  const int wm = w >> 1, wn = w & 1;
  const int lr = l >> 3, lc = (l & 7) * 8;

  f32x4 acc[4][4];
#pragma unroll
  for (int i = 0; i < 4; ++i)
#pragma unroll
    for (int j = 0; j < 4; ++j) acc[i][j] = (f32x4){0.f, 0.f, 0.f, 0.f};

  for (int k0 = 0; k0 < DMODEL; k0 += 64) {
#pragma unroll
    for (int i = 0; i < 4; ++i) {
      GLD_LDS16(A + (size_t)(m0 + w * 32 + i * 8 + lr) * DMODEL + k0 + lc,
                &As[(w * 32 + i * 8) * 64]);
      GLD_LDS16(Bw + (size_t)(w * 32 + i * 8 + lr) * DMODEL + k0 + lc,
                &Bs[(w * 32 + i * 8) * 64]);
    }
    __syncthreads();
#pragma unroll
    for (int t = 0; t < 2; ++t) {
      bf16x8 af[4], bf[4];
#pragma unroll
      for (int mi = 0; mi < 4; ++mi)
        af[mi] = *(const bf16x8*)&As[(wm * 64 + mi * 16 + ll) * 64 + t * 32 + lg * 8];
#pragma unroll
      for (int ni = 0; ni < 4; ++ni)
        bf[ni] = *(const bf16x8*)&Bs[(wn * 64 + ni * 16 + ll) * 64 + t * 32 + lg * 8];
#pragma unroll
      for (int mi = 0; mi < 4; ++mi)
#pragma unroll
        for (int ni = 0; ni < 4; ++ni)
          acc[mi][ni] = __builtin_amdgcn_mfma_f32_16x16x32_bf16(
              af[mi], bf[ni], acc[mi][ni], 0, 0, 0);
    }
    __syncthreads();
  }

  if (nblk < 2) {  // Q or K: row-major [4096][768]; Q scaled by 1/8
    unsigned short* o = nblk ? Ks : Qs;
    const float sc = nblk ? 1.f : 0.125f;
#pragma unroll
    for (int mi = 0; mi < 4; ++mi)
#pragma unroll
      for (int ni = 0; ni < 4; ++ni) {
        const int col = n0 + wn * 64 + ni * 16 + ll;
        const int rowb = m0 + wm * 64 + mi * 16 + lg * 4;
#pragma unroll
        for (int r = 0; r < 4; ++r)
          o[(size_t)(rowb + r) * 768 + col] = f2bf(acc[mi][ni][r] * sc);
      }
  } else {  // V^T: (B,H,64,S)
#pragma unroll
    for (int mi = 0; mi < 4; ++mi)
#pragma unroll
      for (int ni = 0; ni < 4; ++ni) {
        const int col = n0 + wn * 64 + ni * 16 + ll;
        const int row = m0 + wm * 64 + mi * 16 + lg * 4;
        const int bb = row >> 11, sidx = row & (S_LEN - 1);
        const size_t base =
            ((size_t)(bb * NH + (col >> 6)) * 64 + (col & 63)) * S_LEN + sidx;
        us4 pk = { f2bf(acc[mi][ni][0]), f2bf(acc[mi][ni][1]),
                   f2bf(acc[mi][ni][2]), f2bf(acc[mi][ni][3]) };
        *(us4*)&VT[base] = pk;
      }
  }
}

// ---------------- output projection GEMM (f32 out), 128x128 tile ----------
__global__ __launch_bounds__(256, 2)
void gemm_proj(const unsigned short* __restrict__ A,
               const unsigned short* __restrict__ Bw,
               float* __restrict__ o) {
  __shared__ unsigned short As[128 * 64];
  __shared__ unsigned short Bs[128 * 64];
  const int m0 = blockIdx.x * 128, n0 = blockIdx.y * 128;
  const int tid = threadIdx.x, w = tid >> 6, l = tid & 63;
  const int lg = l >> 4, ll = l & 15;
  const int wm = w >> 1, wn = w & 1;
  const int lr = l >> 3, lc = (l & 7) * 8;

  f32x4 acc[4][4];
#pragma unroll
  for (int i = 0; i < 4; ++i)
#pragma unroll
    for (int j = 0; j < 4; ++j) acc[i][j] = (f32x4){0.f, 0.f, 0.f, 0.f};

  for (int k0 = 0; k0 < DMODEL; k0 += 64) {
#pragma unroll
    for (int i = 0; i < 4; ++i) {
      GLD_LDS16(A + (size_t)(m0 + w * 32 + i * 8 + lr) * DMODEL + k0 + lc,
                &As[(w * 32 + i * 8) * 64]);
      GLD_LDS16(Bw + (size_t)(n0 + w * 32 + i * 8 + lr) * DMODEL + k0 + lc,
                &Bs[(w * 32 + i * 8) * 64]);
    }
    __syncthreads();
#pragma unroll
    for (int t = 0; t < 2; ++t) {
      bf16x8 af[4], bf[4];
#pragma unroll
      for (int mi = 0; mi < 4; ++mi)
        af[mi] = *(const bf16x8*)&As[(wm * 64 + mi * 16 + ll) * 64 + t * 32 + lg * 8];
#pragma unroll
      for (int ni = 0; ni < 4; ++ni)
        bf[ni] = *(const bf16x8*)&Bs[(wn * 64 + ni * 16 + ll) * 64 + t * 32 + lg * 8];
#pragma unroll
      for (int mi = 0; mi < 4; ++mi)
#pragma unroll
        for (int ni = 0; ni < 4; ++ni)
          acc[mi][ni] = __builtin_amdgcn_mfma_f32_16x16x32_bf16(
              af[mi], bf[ni], acc[mi][ni], 0, 0, 0);
    }
    __syncthreads();
  }

#pragma unroll
  for (int mi = 0; mi < 4; ++mi)
#pragma unroll
    for (int ni = 0; ni < 4; ++ni) {
      const int col = n0 + wn * 64 + ni * 16 + ll;
      const int rowb = m0 + wm * 64 + mi * 16 + lg * 4;
#pragma unroll
      for (int r = 0; r < 4; ++r)
        o[(size_t)(rowb + r) * DMODEL + col] = acc[mi][ni][r];
    }
}

// -------- attn pass 1a: PARTIAL (m,l) per (q-tile, 8-tile k-chunk) --------
// XCD-pinned: bid&7 selects XCD; all blocks of one (h,b) land on one XCD
// so its K panel (256KB) stays L2-resident (3 hb-groups/XCD = 1.5MB < 4MB).
__global__ __launch_bounds__(256, 3)
void attn_mlp(const unsigned short* __restrict__ Qp,
              const unsigned short* __restrict__ Kp,
              float2* __restrict__ mlpart) {
  const int bid = blockIdx.x;
  const int j = bid >> 3;                      // 0..239
  const int hbg = (bid & 7) + 8 * (j % 3);     // 0..23, pinned per XCD
  const int s = j / 3;                         // 0..79, ascending (heavy-first)
  const int h = hbg >> 1, b = hbg & 1;
  int qt, ck;
  if (s < 32)      { ck = 0; qt = 31 - s; }
  else if (s < 56) { ck = 1; qt = 31 - (s - 32); }
  else if (s < 72) { ck = 2; qt = 31 - (s - 56); }
  else             { ck = 3; qt = 31 - (s - 72); }
  const int ktlo = ck * 8;
  const int kthi = (qt < ktlo + 7) ? qt : (ktlo + 7);

  const int tid = threadIdx.x, w = tid >> 6, l = tid & 63;
  const int lg = l >> 4, ll = l & 15;

  const unsigned short* kbp = Kp + (size_t)b * S_LEN * DMODEL + h * 64;
  const int q0 = qt * 64 + w * 16;

  bf16x8 qf[2];
  {
    const unsigned short* qb =
        Qp + (size_t)(b * S_LEN + q0 + ll) * DMODEL + h * 64 + lg * 8;
    qf[0] = *(const bf16x8*)qb;
    qf[1] = *(const bf16x8*)(qb + 32);
  }
  int rowg[4];
#pragma unroll
  for (int r = 0; r < 4; ++r) rowg[r] = q0 + lg * 4 + r;

  float m[4], lsum[4];
#pragma unroll
  for (int r = 0; r < 4; ++r) { m[r] = -1e30f; lsum[r] = 0.f; }

  auto LOADK = [&](bf16x8* kf, int kt) {
#pragma unroll
    for (int t = 0; t < 2; ++t)
#pragma unroll
      for (int nb = 0; nb < 4; ++nb)
        kf[t * 4 + nb] = *(const bf16x8*)(kbp +
            (size_t)(kt * 64 + nb * 16 + ll) * DMODEL + t * 32 + lg * 8);
  };

  auto P1TILE = [&](const bf16x8* kf, int kt) {
    f32x4 sv[4];
#pragma unroll
    for (int nb = 0; nb < 4; ++nb) sv[nb] = (f32x4){0.f, 0.f, 0.f, 0.f};
#pragma unroll
    for (int t = 0; t < 2; ++t)
#pragma unroll
      for (int nb = 0; nb < 4; ++nb)
        sv[nb] = __builtin_amdgcn_mfma_f32_16x16x32_bf16(qf[t], kf[t * 4 + nb],
                                                         sv[nb], 0, 0, 0);
    if (kt == qt) {  // diagonal: causal mask
#pragma unroll
      for (int nb = 0; nb < 4; ++nb) {
        const int col = kt * 64 + nb * 16 + ll;
#pragma unroll
        for (int r = 0; r < 4; ++r)
          if (col > rowg[r]) sv[nb][r] = -1e30f;
      }
    }
#pragma unroll
    for (int r = 0; r < 4; ++r) {
      float tm = fmaxf(fmaxf(sv[0][r], sv[1][r]), fmaxf(sv[2][r], sv[3][r]));
      float mn = fmaxf(m[r], tm);
      float te = __expf(sv[0][r] - mn) + __expf(sv[1][r] - mn) +
                 __expf(sv[2][r] - mn) + __expf(sv[3][r] - mn);
      lsum[r] = lsum[r] * __expf(m[r] - mn) + te;
      m[r] = mn;
    }
  };

  {
    bf16x8 ka[8], kb2[8];
    LOADK(ka, ktlo);
    for (int kt = ktlo; kt <= kthi; kt += 2) {
      if (kt + 1 <= kthi) LOADK(kb2, kt + 1);
      P1TILE(ka, kt);
      if (kt + 1 > kthi) break;
      if (kt + 2 <= kthi) LOADK(ka, kt + 2);
      P1TILE(kb2, kt + 1);
    }
  }

  // butterfly combine across the 16 lanes sharing each row
#pragma unroll
  for (int off = 1; off < 16; off <<= 1)
#pragma unroll
    for (int r = 0; r < 4; ++r) {
      float om = __shfl_xor(m[r], off, 64);
      float ol = __shfl_xor(lsum[r], off, 64);
      float mn = fmaxf(m[r], om);
      lsum[r] = lsum[r] * __expf(m[r] - mn) + ol * __expf(om - mn);
      m[r] = mn;
    }

  if (ll == 0) {
    float2* mp = mlpart + ((size_t)(b * NH + h) * S_LEN) * 4;
#pragma unroll
    for (int r = 0; r < 4; ++r)
      mp[(size_t)rowg[r] * 4 + ck] = make_float2(m[r], lsum[r]);
  }
}

// -------- attn pass 1b: combine <=4 chunk partials -> (m, 1/l) --------
__global__ void ml_combine(const float2* __restrict__ mlpart,
                           float2* __restrict__ mlbuf) {
  int i = blockIdx.x * blockDim.x + threadIdx.x;  // 0 .. 24*2048-1
  int row = i & (S_LEN - 1);
  int nck = (row >> 9) + 1;  // qt>>3 + 1
  const float2* p = mlpart + (size_t)i * 4;
  float m = -1e30f, l = 0.f;
  for (int c = 0; c < nck; ++c) {
    float2 t = p[c];
    float mn = fmaxf(m, t.x);
    l = l * __expf(m - mn) + t.y * __expf(t.x - mn);
    m = mn;
  }
  mlbuf[i] = make_float2(m, 1.f / l);
}

// ---------------- attn pass 2: 16-tile-chunk P write + PV ----------------
// XCD-pinned like attn_mlp: K+V panels (512KB/(h,b), 3 hb/XCD) stay in L2,
// so tile loads hit L2 instead of contending with the P-store HBM stream.
__global__ __launch_bounds__(256, 3)
void attn_p2(const unsigned short* __restrict__ Qp,
             const unsigned short* __restrict__ Kp,
             const unsigned short* __restrict__ VTp,
             const float2* __restrict__ mlbuf,
             float* __restrict__ attnw,
             float* __restrict__ ctx0,
             float* __restrict__ ctx1) {
  const int bid = blockIdx.x;
  const int j = bid >> 3;                      // 0..191
  const int hbg = (bid & 7) + 8 * (j % 3);     // 0..23, pinned per XCD
  const int slot = j / 3;                      // 0..63
  const int h = hbg >> 1, b = hbg & 1;
  // slot -> (chunk, qt), sorted by value-tile count desc
  int qt, ck;
  if (slot <= 16)      { ck = 0; qt = 15 + slot; }
  else if (slot == 17) { ck = 1; qt = 31; }
  else if (slot < 48)  { int u = slot - 18; int k = 15 - (u >> 1);
                         if (u & 1) { ck = 1; qt = k + 15; } else { ck = 0; qt = k - 1; } }
  else                 { ck = 1; qt = slot - 48; }

  const int ktlo = ck * 16;
  const int kthi = (qt < ktlo + 15) ? qt : (ktlo + 15);  // last value tile
  const bool hasval = (ktlo <= qt);

  const int tid = threadIdx.x, w = tid >> 6, l = tid & 63;
  const int lg = l >> 4, ll = l & 15;
  __shared__ float pf32[4][1024];  // 16x64 f32 per wave (private)
  float* pfw = &pf32[w][0];

  const unsigned short* kbp = Kp + (size_t)b * S_LEN * DMODEL + h * 64;
  const unsigned short* vbp = VTp + ((size_t)(b * NH + h)) * 64 * S_LEN;
  float* pbase = attnw + ((size_t)(b * NH + h)) * S_LEN * S_LEN;

  const int q0 = qt * 64 + w * 16;
  int rowg[4];
#pragma unroll
  for (int r = 0; r < 4; ++r) rowg[r] = q0 + lg * 4 + r;

  if (hasval) {
    bf16x8 qf[2];
    {
      const unsigned short* qb =
          Qp + (size_t)(b * S_LEN + q0 + ll) * DMODEL + h * 64 + lg * 8;
      qf[0] = *(const bf16x8*)qb;
      qf[1] = *(const bf16x8*)(qb + 32);
    }
    float m[4], linv[4];
    {
      const float2* mlb = mlbuf + (size_t)(b * NH + h) * S_LEN;
#pragma unroll
      for (int r = 0; r < 4; ++r) {
        float2 t = mlb[rowg[r]];
        m[r] = t.x;
        linv[r] = t.y;
      }
    }

    f32x4 cacc[4];
#pragma unroll
    for (int nb = 0; nb < 4; ++nb) cacc[nb] = (f32x4){0.f, 0.f, 0.f, 0.f};

    bf16x8 kf[8], vf[8];
#pragma unroll
    for (int t = 0; t < 2; ++t)
#pragma unroll
      for (int nb = 0; nb < 4; ++nb) {
        kf[t * 4 + nb] = *(const bf16x8*)(kbp +
            (size_t)(ktlo * 64 + nb * 16 + ll) * DMODEL + t * 32 + lg * 8);
        vf[t * 4 + nb] = *(const bf16x8*)(vbp +
            (size_t)(nb * 16 + ll) * S_LEN + ktlo * 64 + t * 32 + lg * 8);
      }

    for (int kt = ktlo; kt <= kthi; ++kt) {
      // QK^T
      f32x4 sv[4];
#pragma unroll
      for (int nb = 0; nb < 4; ++nb) sv[nb] = (f32x4){0.f, 0.f, 0.f, 0.f};
#pragma unroll
      for (int t = 0; t < 2; ++t)
#pragma unroll
        for (int nb = 0; nb < 4; ++nb)
          sv[nb] = __builtin_amdgcn_mfma_f32_16x16x32_bf16(qf[t], kf[t * 4 + nb],
                                                           sv[nb], 0, 0, 0);
      // p (masked -> exact 0) -> f32 LDS (swz: col ^ ((row>>2)&1)<<4)
#pragma unroll
      for (int nb = 0; nb < 4; ++nb) {
        const int col = kt * 64 + nb * 16 + ll;
#pragma unroll
        for (int r = 0; r < 4; ++r) {
          float p = (col <= rowg[r]) ? __expf(sv[nb][r] - m[r]) * linv[r] : 0.f;
          const int rl = lg * 4 + r;
          pfw[rl * 64 + ((nb * 16 + ll) ^ ((lg & 1) << 4))] = p;
        }
      }
      // PV A-frags: read f32 tile (row=ll, cols t*32+lg*8..+8) + cvt to bf16
      bf16x8 pf[2];
#pragma unroll
      for (int t = 0; t < 2; ++t) {
        const int c0 = (t * 32 + lg * 8) ^ (((ll >> 2) & 1) << 4);
        f32x4 lo = *(const f32x4*)&pfw[ll * 64 + c0];
        f32x4 hi = *(const f32x4*)&pfw[ll * 64 + c0 + 4];
        union { us4 hh[2]; bf16x8 v; } u;
        u.hh[0] = (us4){ f2bf(lo[0]), f2bf(lo[1]), f2bf(lo[2]), f2bf(lo[3]) };
        u.hh[1] = (us4){ f2bf(hi[0]), f2bf(hi[1]), f2bf(hi[2]), f2bf(hi[3]) };
        pf[t] = u.v;
      }
      // PV
#pragma unroll
      for (int t = 0; t < 2; ++t)
#pragma unroll
        for (int nb = 0; nb < 4; ++nb)
          cacc[nb] = __builtin_amdgcn_mfma_f32_16x16x32_bf16(
              pf[t], vf[t * 4 + nb], cacc[nb], 0, 0, 0);
      // issue next tile's loads BEFORE this tile's stores
      if (kt < kthi) {
#pragma unroll
        for (int t = 0; t < 2; ++t)
#pragma unroll
          for (int nb = 0; nb < 4; ++nb) {
            kf[t * 4 + nb] = *(const bf16x8*)(kbp +
                (size_t)((kt + 1) * 64 + nb * 16 + ll) * DMODEL + t * 32 + lg * 8);
            vf[t * 4 + nb] = *(const bf16x8*)(vbp +
                (size_t)(nb * 16 + ll) * S_LEN + (kt + 1) * 64 + t * 32 + lg * 8);
          }
      }
      // coalesced P stores: 4 passes, each wave instr = 4 rows x 256B lines
#pragma unroll
      for (int ps = 0; ps < 4; ++ps) {
        const int row = ps * 4 + lg;                       // (row>>2)&1 == ps&1
        const int cb = (ll * 4) ^ ((ps & 1) << 4);
        f32x4 pv = *(const f32x4*)&pfw[row * 64 + cb];
        *(f32x4*)&pbase[(size_t)(q0 + row) * S_LEN + kt * 64 + ll * 4] = pv;
      }
    }

    // PV partial -> ctx0/ctx1, coalesced via same f32 LDS tile
#pragma unroll
    for (int nb = 0; nb < 4; ++nb)
#pragma unroll
      for (int r = 0; r < 4; ++r) {
        const int rl = lg * 4 + r;
        pfw[rl * 64 + ((nb * 16 + ll) ^ ((lg & 1) << 4))] = cacc[nb][r];
      }
    float* co = ck ? ctx1 : ctx0;
#pragma unroll
    for (int ps = 0; ps < 4; ++ps) {
      const int row = ps * 4 + lg;
      const int cb = (ll * 4) ^ ((ps & 1) << 4);
      f32x4 cv = *(const f32x4*)&pfw[row * 64 + cb];
      *(f32x4*)&co[(size_t)(b * S_LEN + q0 + row) * DMODEL + h * 64 + ll * 4] = cv;
    }
  }

  // zero-fill masked columns inside this chunk (overwrite 0xAA poison)
  const int zs = ((qt + 1) * 64 > ktlo * 64) ? (qt + 1) * 64 : ktlo * 64;
  const int ze = (ktlo + 16) * 64;
  if (zs < ze) {
    f32x4 z = (f32x4){0.f, 0.f, 0.f, 0.f};
    for (int rr = 0; rr < 16; ++rr) {
      float* dst = pbase + (size_t)(q0 + rr) * S_LEN;
      for (int c = zs + l * 4; c < ze; c += 256)
        *(f32x4*)(dst + c) = z;
    }
  }
}

extern "C" void kernel_launch(void* const* d_in, const int* in_sizes, int n_in,
                              void* d_out, int out_size, void* d_ws, size_t ws_size,
                              hipStream_t stream) {
  const float* q_in = (const float*)d_in[0];
  const float* k_in = (const float*)d_in[1];
  const float* v_in = (const float*)d_in[2];
  // d_in[3] = mask: causal triu(k=1), hardcoded in attn kernels
  const float* wq = (const float*)d_in[4];
  const float* wk = (const float*)d_in[5];
  const float* wv = (const float*)d_in[6];
  const float* wo = (const float*)d_in[7];

  const int BSD = BATCH * S_LEN * DMODEL;  // 3145728
  const int DD = DMODEL * DMODEL;          // 589824
  const int M = BATCH * S_LEN;             // 4096

  char* ws = (char*)d_ws;
  unsigned short* qbf = (unsigned short*)ws;  ws += (size_t)BSD * 2;
  unsigned short* kbf = (unsigned short*)ws;  ws += (size_t)BSD * 2;
  unsigned short* vbf = (unsigned short*)ws;  ws += (size_t)BSD * 2;
  unsigned short* wqb = (unsigned short*)ws;  ws += (size_t)DD * 2;   // contiguous
  unsigned short* wkb = (unsigned short*)ws;  ws += (size_t)DD * 2;   //  W3 =
  unsigned short* wvb = (unsigned short*)ws;  ws += (size_t)DD * 2;   //  [2304][768]
  unsigned short* wob = (unsigned short*)ws;  ws += (size_t)DD * 2;
  unsigned short* Qs  = (unsigned short*)ws;  ws += (size_t)BSD * 2;
  unsigned short* Ks  = (unsigned short*)ws;  ws += (size_t)BSD * 2;
  unsigned short* VT  = (unsigned short*)ws;  ws += (size_t)BSD * 2;
  unsigned short* ctx = (unsigned short*)ws;  ws += (size_t)BSD * 2;
  float* ctx0 = (float*)ws;                   ws += (size_t)BSD * 4;
  float* ctx1 = (float*)ws;                   ws += (size_t)BSD * 4;
  float2* mlbuf = (float2*)ws;                ws += (size_t)M * NH * sizeof(float2);
  float2* mlpart = (float2*)ws;               ws += (size_t)M * NH * 4 * sizeof(float2);
  (void)wkb; (void)wvb;

  float* out_proj = (float*)d_out;
  float* attnw = (float*)d_out + BSD;

  cvt3_kernel<<<3 * N8_BSD / 256, 256, 0, stream>>>(q_in, k_in, v_in, qbf, ctx1);
  cvt4_kernel<<<4 * N8_DD / 256, 256, 0, stream>>>(wq, wk, wv, wo, wqb);

  gemm_qkv<<<dim3(M / 128, 2304 / 128), 256, 0, stream>>>(qbf, kbf, vbf, wqb,
                                                          Qs, Ks, VT);

  attn_mlp<<<80 * NH * BATCH, 256, 0, stream>>>(Qs, Ks, mlpart);
  ml_combine<<<M * NH / 256, 256, 0, stream>>>(mlpart, mlbuf);
  attn_p2<<<64 * NH * BATCH, 256, 0, stream>>>(Qs, Ks, VT, mlbuf, attnw,
                                               ctx0, ctx1);
  ctx_reduce<<<BSD / 4 / 256, 256, 0, stream>>>(ctx0, ctx1, ctx);

  gemm_proj<<<dim3(M / 128, DMODEL / 128), 256, 0, stream>>>(ctx, wob, out_proj);
}

// Round 10
// 275.444 us; speedup vs baseline: 1.0131x; 1.0131x over previous
//
#include <hip/hip_runtime.h>

#define BATCH 2
#define S_LEN 2048
#define NH 12
#define DMODEL 768
// DK = 64, scale = 1/8

#define N8_BSD (BATCH * S_LEN * DMODEL / 8)  // 393216
#define N8_DD (DMODEL * DMODEL / 8)          // 73728

typedef __attribute__((ext_vector_type(8))) short bf16x8;
typedef __attribute__((ext_vector_type(4))) float f32x4;
typedef __attribute__((ext_vector_type(4))) unsigned short us4;

__device__ __forceinline__ unsigned short f2bf(float f) {
  union { float f; unsigned int u; } v; v.f = f;
  unsigned int r = v.u + 0x7fffu + ((v.u >> 16) & 1u);  // RNE
  return (unsigned short)(r >> 16);
}

// ------- f32 -> bf16 converts (8 elems/thread); cvt3 also zeroes ctx1 -------
__global__ void cvt3_kernel(const float* __restrict__ s0,
                            const float* __restrict__ s1,
                            const float* __restrict__ s2,
                            unsigned short* __restrict__ dst,
                            float* __restrict__ ctx1) {
  int i = blockIdx.x * blockDim.x + threadIdx.x;  // 0 .. 3*N8_BSD-1 (exact)
  int j = i / N8_BSD;
  int k = i - j * N8_BSD;
  const float* s = (j == 0) ? s0 : (j == 1) ? s1 : s2;
  const float4* sp = (const float4*)s;
  float4 a = sp[k * 2], b = sp[k * 2 + 1];
  us4 o0 = { f2bf(a.x), f2bf(a.y), f2bf(a.z), f2bf(a.w) };
  us4 o1 = { f2bf(b.x), f2bf(b.y), f2bf(b.z), f2bf(b.w) };
  us4* d = (us4*)dst;
  d[i * 2] = o0;
  d[i * 2 + 1] = o1;
  if (j == 0) {  // zero ctx1 partial buffer (BSD f32 = exactly this segment)
    f32x4 z = (f32x4){0.f, 0.f, 0.f, 0.f};
    f32x4* c = (f32x4*)ctx1;
    c[k * 2] = z;
    c[k * 2 + 1] = z;
  }
}

__global__ void cvt4_kernel(const float* __restrict__ s0,
                            const float* __restrict__ s1,
                            const float* __restrict__ s2,
                            const float* __restrict__ s3,
                            unsigned short* __restrict__ dst) {
  int i = blockIdx.x * blockDim.x + threadIdx.x;  // 0 .. 4*N8_DD-1 (exact)
  int j = i / N8_DD;
  int k = i - j * N8_DD;
  const float* s = (j == 0) ? s0 : (j == 1) ? s1 : (j == 2) ? s2 : s3;
  const float4* sp = (const float4*)s;
  float4 a = sp[k * 2], b = sp[k * 2 + 1];
  us4 o0 = { f2bf(a.x), f2bf(a.y), f2bf(a.z), f2bf(a.w) };
  us4 o1 = { f2bf(b.x), f2bf(b.y), f2bf(b.z), f2bf(b.w) };
  us4* d = (us4*)dst;
  d[i * 2] = o0;
  d[i * 2 + 1] = o1;
}

// ------- reduce: ctx_bf16 = f2bf(ctx0 + ctx1), 4 elems/thread -------
__global__ void ctx_reduce(const float* __restrict__ c0,
                           const float* __restrict__ c1,
                           unsigned short* __restrict__ o) {
  int i = blockIdx.x * blockDim.x + threadIdx.x;  // 0 .. BSD/4-1
  float4 a = ((const float4*)c0)[i];
  float4 b = ((const float4*)c1)[i];
  us4 r = { f2bf(a.x + b.x), f2bf(a.y + b.y), f2bf(a.z + b.z), f2bf(a.w + b.w) };
  ((us4*)o)[i] = r;
}

#define GLD_LDS16(g, l)                                                    \
  __builtin_amdgcn_global_load_lds(                                        \
      (const __attribute__((address_space(1))) unsigned int*)(g),          \
      (__attribute__((address_space(3))) unsigned int*)(l), 16, 0, 0)

// ---------------- fused QKV projection GEMM, 128x128 tile ----------------
__global__ __launch_bounds__(256, 2)
void gemm_qkv(const unsigned short* __restrict__ Aq,
              const unsigned short* __restrict__ Ak,
              const unsigned short* __restrict__ Av,
              const unsigned short* __restrict__ W3,
              unsigned short* __restrict__ Qs,
              unsigned short* __restrict__ Ks,
              unsigned short* __restrict__ VT) {
  __shared__ unsigned short As[128 * 64];
  __shared__ unsigned short Bs[128 * 64];
  const int m0 = blockIdx.x * 128;
  const int n0g = blockIdx.y * 128;
  const int nblk = n0g / 768;         // 0=Q 1=K 2=V (uniform per block)
  const int n0 = n0g - nblk * 768;
  const unsigned short* A = (nblk == 0) ? Aq : (nblk == 1) ? Ak : Av;
  const unsigned short* Bw = W3 + (size_t)n0g * DMODEL;
  const int tid = threadIdx.x, w = tid >> 6, l = tid & 63;
  const int lg = l >> 4, ll = l & 15;
  const int wm = w >> 1, wn = w & 1;
  const int lr = l >> 3, lc = (l & 7) * 8;

  f32x4 acc[4][4];
#pragma unroll
  for (int i = 0; i < 4; ++i)
#pragma unroll
    for (int j = 0; j < 4; ++j) acc[i][j] = (f32x4){0.f, 0.f, 0.f, 0.f};

  for (int k0 = 0; k0 < DMODEL; k0 += 64) {
#pragma unroll
    for (int i = 0; i < 4; ++i) {
      GLD_LDS16(A + (size_t)(m0 + w * 32 + i * 8 + lr) * DMODEL + k0 + lc,
                &As[(w * 32 + i * 8) * 64]);
      GLD_LDS16(Bw + (size_t)(w * 32 + i * 8 + lr) * DMODEL + k0 + lc,
                &Bs[(w * 32 + i * 8) * 64]);
    }
    __syncthreads();
#pragma unroll
    for (int t = 0; t < 2; ++t) {
      bf16x8 af[4], bf[4];
#pragma unroll
      for (int mi = 0; mi < 4; ++mi)
        af[mi] = *(const bf16x8*)&As[(wm * 64 + mi * 16 + ll) * 64 + t * 32 + lg * 8];
#pragma unroll
      for (int ni = 0; ni < 4; ++ni)
        bf[ni] = *(const bf16x8*)&Bs[(wn * 64 + ni * 16 + ll) * 64 + t * 32 + lg * 8];
#pragma unroll
      for (int mi = 0; mi < 4; ++mi)
#pragma unroll
        for (int ni = 0; ni < 4; ++ni)
          acc[mi][ni] = __builtin_amdgcn_mfma_f32_16x16x32_bf16(
              af[mi], bf[ni], acc[mi][ni], 0, 0, 0);
    }
    __syncthreads();
  }

  if (nblk < 2) {  // Q or K: row-major [4096][768]; Q scaled by 1/8
    unsigned short* o = nblk ? Ks : Qs;
    const float sc = nblk ? 1.f : 0.125f;
#pragma unroll
    for (int mi = 0; mi < 4; ++mi)
#pragma unroll
      for (int ni = 0; ni < 4; ++ni) {
        const int col = n0 + wn * 64 + ni * 16 + ll;
        const int rowb = m0 + wm * 64 + mi * 16 + lg * 4;
#pragma unroll
        for (int r = 0; r < 4; ++r)
          o[(size_t)(rowb + r) * 768 + col] = f2bf(acc[mi][ni][r] * sc);
      }
  } else {  // V^T: (B,H,64,S)
#pragma unroll
    for (int mi = 0; mi < 4; ++mi)
#pragma unroll
      for (int ni = 0; ni < 4; ++ni) {
        const int col = n0 + wn * 64 + ni * 16 + ll;
        const int row = m0 + wm * 64 + mi * 16 + lg * 4;
        const int bb = row >> 11, sidx = row & (S_LEN - 1);
        const size_t base =
            ((size_t)(bb * NH + (col >> 6)) * 64 + (col & 63)) * S_LEN + sidx;
        us4 pk = { f2bf(acc[mi][ni][0]), f2bf(acc[mi][ni][1]),
                   f2bf(acc[mi][ni][2]), f2bf(acc[mi][ni][3]) };
        *(us4*)&VT[base] = pk;
      }
  }
}

// ---------------- output projection GEMM (f32 out), 128x128 tile ----------
__global__ __launch_bounds__(256, 2)
void gemm_proj(const unsigned short* __restrict__ A,
               const unsigned short* __restrict__ Bw,
               float* __restrict__ o) {
  __shared__ unsigned short As[128 * 64];
  __shared__ unsigned short Bs[128 * 64];
  const int m0 = blockIdx.x * 128, n0 = blockIdx.y * 128;
  const int tid = threadIdx.x, w = tid >> 6, l = tid & 63;
  const int lg = l >> 4, ll = l & 15;
  const int wm = w >> 1, wn = w & 1;
  const int lr = l >> 3, lc = (l & 7) * 8;

  f32x4 acc[4][4];
#pragma unroll
  for (int i = 0; i < 4; ++i)
#pragma unroll
    for (int j = 0; j < 4; ++j) acc[i][j] = (f32x4){0.f, 0.f, 0.f, 0.f};

  for (int k0 = 0; k0 < DMODEL; k0 += 64) {
#pragma unroll
    for (int i = 0; i < 4; ++i) {
      GLD_LDS16(A + (size_t)(m0 + w * 32 + i * 8 + lr) * DMODEL + k0 + lc,
                &As[(w * 32 + i * 8) * 64]);
      GLD_LDS16(Bw + (size_t)(n0 + w * 32 + i * 8 + lr) * DMODEL + k0 + lc,
                &Bs[(w * 32 + i * 8) * 64]);
    }
    __syncthreads();
#pragma unroll
    for (int t = 0; t < 2; ++t) {
      bf16x8 af[4], bf[4];
#pragma unroll
      for (int mi = 0; mi < 4; ++mi)
        af[mi] = *(const bf16x8*)&As[(wm * 64 + mi * 16 + ll) * 64 + t * 32 + lg * 8];
#pragma unroll
      for (int ni = 0; ni < 4; ++ni)
        bf[ni] = *(const bf16x8*)&Bs[(wn * 64 + ni * 16 + ll) * 64 + t * 32 + lg * 8];
#pragma unroll
      for (int mi = 0; mi < 4; ++mi)
#pragma unroll
        for (int ni = 0; ni < 4; ++ni)
          acc[mi][ni] = __builtin_amdgcn_mfma_f32_16x16x32_bf16(
              af[mi], bf[ni], acc[mi][ni], 0, 0, 0);
    }
    __syncthreads();
  }

#pragma unroll
  for (int mi = 0; mi < 4; ++mi)
#pragma unroll
    for (int ni = 0; ni < 4; ++ni) {
      const int col = n0 + wn * 64 + ni * 16 + ll;
      const int rowb = m0 + wm * 64 + mi * 16 + lg * 4;
#pragma unroll
      for (int r = 0; r < 4; ++r)
        o[(size_t)(rowb + r) * DMODEL + col] = acc[mi][ni][r];
    }
}

// -------- attn pass 1a: PARTIAL (m,l) per (q-tile, 8-tile k-chunk) --------
// No register prefetch (direct load->use, K is L2-resident), low VGPR,
// 4 waves/SIMD for latency hiding.
__global__ __launch_bounds__(256, 4)
void attn_mlp(const unsigned short* __restrict__ Qp,
              const unsigned short* __restrict__ Kp,
              float2* __restrict__ mlpart) {
  const int idx = blockIdx.x;
  const int s = idx / (NH * BATCH);  // 0..79
  const int hb = idx % (NH * BATCH);
  const int h = hb >> 1, b = hb & 1;
  int qt, ck;
  if (s < 32)      { ck = 0; qt = 31 - s; }
  else if (s < 56) { ck = 1; qt = 31 - (s - 32); }
  else if (s < 72) { ck = 2; qt = 31 - (s - 56); }
  else             { ck = 3; qt = 31 - (s - 72); }
  const int ktlo = ck * 8;
  const int kthi = (qt < ktlo + 7) ? qt : (ktlo + 7);

  const int tid = threadIdx.x, w = tid >> 6, l = tid & 63;
  const int lg = l >> 4, ll = l & 15;

  const unsigned short* kbp = Kp + (size_t)b * S_LEN * DMODEL + h * 64;
  const int q0 = qt * 64 + w * 16;

  bf16x8 qf[2];
  {
    const unsigned short* qb =
        Qp + (size_t)(b * S_LEN + q0 + ll) * DMODEL + h * 64 + lg * 8;
    qf[0] = *(const bf16x8*)qb;
    qf[1] = *(const bf16x8*)(qb + 32);
  }
  int rowg[4];
#pragma unroll
  for (int r = 0; r < 4; ++r) rowg[r] = q0 + lg * 4 + r;

  float m[4], lsum[4];
#pragma unroll
  for (int r = 0; r < 4; ++r) { m[r] = -1e30f; lsum[r] = 0.f; }

  for (int kt = ktlo; kt <= kthi; ++kt) {
    bf16x8 kf[8];
#pragma unroll
    for (int t = 0; t < 2; ++t)
#pragma unroll
      for (int nb = 0; nb < 4; ++nb)
        kf[t * 4 + nb] = *(const bf16x8*)(kbp +
            (size_t)(kt * 64 + nb * 16 + ll) * DMODEL + t * 32 + lg * 8);
    f32x4 sv[4];
#pragma unroll
    for (int nb = 0; nb < 4; ++nb) sv[nb] = (f32x4){0.f, 0.f, 0.f, 0.f};
#pragma unroll
    for (int t = 0; t < 2; ++t)
#pragma unroll
      for (int nb = 0; nb < 4; ++nb)
        sv[nb] = __builtin_amdgcn_mfma_f32_16x16x32_bf16(qf[t], kf[t * 4 + nb],
                                                         sv[nb], 0, 0, 0);
    if (kt == qt) {  // diagonal: causal mask
#pragma unroll
      for (int nb = 0; nb < 4; ++nb) {
        const int col = kt * 64 + nb * 16 + ll;
#pragma unroll
        for (int r = 0; r < 4; ++r)
          if (col > rowg[r]) sv[nb][r] = -1e30f;
      }
    }
#pragma unroll
    for (int r = 0; r < 4; ++r) {
      float tm = fmaxf(fmaxf(sv[0][r], sv[1][r]), fmaxf(sv[2][r], sv[3][r]));
      float mn = fmaxf(m[r], tm);
      float te = __expf(sv[0][r] - mn) + __expf(sv[1][r] - mn) +
                 __expf(sv[2][r] - mn) + __expf(sv[3][r] - mn);
      lsum[r] = lsum[r] * __expf(m[r] - mn) + te;
      m[r] = mn;
    }
  }

  // butterfly combine across the 16 lanes sharing each row
#pragma unroll
  for (int off = 1; off < 16; off <<= 1)
#pragma unroll
    for (int r = 0; r < 4; ++r) {
      float om = __shfl_xor(m[r], off, 64);
      float ol = __shfl_xor(lsum[r], off, 64);
      float mn = fmaxf(m[r], om);
      lsum[r] = lsum[r] * __expf(m[r] - mn) + ol * __expf(om - mn);
      m[r] = mn;
    }

  if (ll == 0) {
    float2* mp = mlpart + ((size_t)(b * NH + h) * S_LEN) * 4;
#pragma unroll
    for (int r = 0; r < 4; ++r)
      mp[(size_t)rowg[r] * 4 + ck] = make_float2(m[r], lsum[r]);
  }
}

// -------- attn pass 1b: combine <=4 chunk partials -> (m, 1/l) --------
__global__ void ml_combine(const float2* __restrict__ mlpart,
                           float2* __restrict__ mlbuf) {
  int i = blockIdx.x * blockDim.x + threadIdx.x;  // 0 .. 24*2048-1
  int row = i & (S_LEN - 1);
  int nck = (row >> 9) + 1;  // qt>>3 + 1
  const float2* p = mlpart + (size_t)i * 4;
  float m = -1e30f, l = 0.f;
  for (int c = 0; c < nck; ++c) {
    float2 t = p[c];
    float mn = fmaxf(m, t.x);
    l = l * __expf(m - mn) + t.y * __expf(t.x - mn);
    m = mn;
  }
  mlbuf[i] = make_float2(m, 1.f / l);
}

// ---------------- attn pass 2: 16-tile-chunk P write + PV ----------------
// No register prefetch (direct load->use; K/V L2-resident). P values for
// TWO k-tiles staged in a 16x128 f32 LDS tile per wave, then stored as one
// 8KB burst (512B/row temporally adjacent) - longer write runs for DRAM.
__global__ __launch_bounds__(256, 3)
void attn_p2(const unsigned short* __restrict__ Qp,
             const unsigned short* __restrict__ Kp,
             const unsigned short* __restrict__ VTp,
             const float2* __restrict__ mlbuf,
             float* __restrict__ attnw,
             float* __restrict__ ctx0,
             float* __restrict__ ctx1) {
  const int idx = blockIdx.x;
  const int slot = idx / (NH * BATCH);  // 0..63
  const int hb = idx % (NH * BATCH);
  const int h = hb >> 1, b = hb & 1;
  // slot -> (chunk, qt), sorted by value-tile count desc
  int qt, ck;
  if (slot <= 16)      { ck = 0; qt = 15 + slot; }
  else if (slot == 17) { ck = 1; qt = 31; }
  else if (slot < 48)  { int u = slot - 18; int k = 15 - (u >> 1);
                         if (u & 1) { ck = 1; qt = k + 15; } else { ck = 0; qt = k - 1; } }
  else                 { ck = 1; qt = slot - 48; }

  const int ktlo = ck * 16;
  const int kthi = (qt < ktlo + 15) ? qt : (ktlo + 15);  // last value tile
  const bool hasval = (ktlo <= qt);

  const int tid = threadIdx.x, w = tid >> 6, l = tid & 63;
  const int lg = l >> 4, ll = l & 15;
  __shared__ float pf32[4][16 * 128];  // 16x128 f32 per wave (2 k-tiles)
  float* pfw = &pf32[w][0];

  const unsigned short* kbp = Kp + (size_t)b * S_LEN * DMODEL + h * 64;
  const unsigned short* vbp = VTp + ((size_t)(b * NH + h)) * 64 * S_LEN;
  float* pbase = attnw + ((size_t)(b * NH + h)) * S_LEN * S_LEN;

  const int q0 = qt * 64 + w * 16;
  int rowg[4];
#pragma unroll
  for (int r = 0; r < 4; ++r) rowg[r] = q0 + lg * 4 + r;

  if (hasval) {
    bf16x8 qf[2];
    {
      const unsigned short* qb =
          Qp + (size_t)(b * S_LEN + q0 + ll) * DMODEL + h * 64 + lg * 8;
      qf[0] = *(const bf16x8*)qb;
      qf[1] = *(const bf16x8*)(qb + 32);
    }
    float m[4], linv[4];
    {
      const float2* mlb = mlbuf + (size_t)(b * NH + h) * S_LEN;
#pragma unroll
      for (int r = 0; r < 4; ++r) {
        float2 t = mlb[rowg[r]];
        m[r] = t.x;
        linv[r] = t.y;
      }
    }

    f32x4 cacc[4];
#pragma unroll
    for (int nb = 0; nb < 4; ++nb) cacc[nb] = (f32x4){0.f, 0.f, 0.f, 0.f};

    for (int ktp = ktlo; ktp <= kthi; ktp += 2) {
      const int nsub = (ktp + 1 <= kthi) ? 2 : 1;
#pragma unroll 2
      for (int sub = 0; sub < nsub; ++sub) {
        const int kt = ktp + sub;
        // K loads (direct)
        bf16x8 kf[8];
#pragma unroll
        for (int t = 0; t < 2; ++t)
#pragma unroll
          for (int nb = 0; nb < 4; ++nb)
            kf[t * 4 + nb] = *(const bf16x8*)(kbp +
                (size_t)(kt * 64 + nb * 16 + ll) * DMODEL + t * 32 + lg * 8);
        // QK^T
        f32x4 sv[4];
#pragma unroll
        for (int nb = 0; nb < 4; ++nb) sv[nb] = (f32x4){0.f, 0.f, 0.f, 0.f};
#pragma unroll
        for (int t = 0; t < 2; ++t)
#pragma unroll
          for (int nb = 0; nb < 4; ++nb)
            sv[nb] = __builtin_amdgcn_mfma_f32_16x16x32_bf16(
                qf[t], kf[t * 4 + nb], sv[nb], 0, 0, 0);
        // p (masked -> exact 0) -> f32 LDS (swz within 64-block)
#pragma unroll
        for (int nb = 0; nb < 4; ++nb) {
          const int col = kt * 64 + nb * 16 + ll;
#pragma unroll
          for (int r = 0; r < 4; ++r) {
            float p = (col <= rowg[r]) ? __expf(sv[nb][r] - m[r]) * linv[r] : 0.f;
            const int rl = lg * 4 + r;
            pfw[rl * 128 + sub * 64 + ((nb * 16 + ll) ^ ((lg & 1) << 4))] = p;
          }
        }
        // PV A-frags: read f32 tile (row=ll) + cvt to bf16
        bf16x8 pf[2];
#pragma unroll
        for (int t = 0; t < 2; ++t) {
          const int c0 = sub * 64 + ((t * 32 + lg * 8) ^ (((ll >> 2) & 1) << 4));
          f32x4 lo = *(const f32x4*)&pfw[ll * 128 + c0];
          f32x4 hi = *(const f32x4*)&pfw[ll * 128 + c0 + 4];
          union { us4 hh[2]; bf16x8 v; } u;
          u.hh[0] = (us4){ f2bf(lo[0]), f2bf(lo[1]), f2bf(lo[2]), f2bf(lo[3]) };
          u.hh[1] = (us4){ f2bf(hi[0]), f2bf(hi[1]), f2bf(hi[2]), f2bf(hi[3]) };
          pf[t] = u.v;
        }
        // V loads (direct) + PV
        bf16x8 vf[8];
#pragma unroll
        for (int t = 0; t < 2; ++t)
#pragma unroll
          for (int nb = 0; nb < 4; ++nb)
            vf[t * 4 + nb] = *(const bf16x8*)(vbp +
                (size_t)(nb * 16 + ll) * S_LEN + kt * 64 + t * 32 + lg * 8);
#pragma unroll
        for (int t = 0; t < 2; ++t)
#pragma unroll
          for (int nb = 0; nb < 4; ++nb)
            cacc[nb] = __builtin_amdgcn_mfma_f32_16x16x32_bf16(
                pf[t], vf[t * 4 + nb], cacc[nb], 0, 0, 0);
      }
      // store burst: 16 rows x (nsub*64) f32, back-to-back full lines
#pragma unroll
      for (int ps = 0; ps < 4; ++ps) {
        const int row = ps * 4 + lg;             // (row>>2)&1 == ps&1
        const int cb = (ll * 4) ^ ((ps & 1) << 4);
        float* drow = &pbase[(size_t)(q0 + row) * S_LEN + ktp * 64];
        f32x4 pv0 = *(const f32x4*)&pfw[row * 128 + cb];
        *(f32x4*)&drow[ll * 4] = pv0;
        if (nsub == 2) {
          f32x4 pv1 = *(const f32x4*)&pfw[row * 128 + 64 + cb];
          *(f32x4*)&drow[64 + ll * 4] = pv1;
        }
      }
    }

    // PV partial -> ctx0/ctx1, coalesced via the LDS tile
#pragma unroll
    for (int nb = 0; nb < 4; ++nb)
#pragma unroll
      for (int r = 0; r < 4; ++r) {
        const int rl = lg * 4 + r;
        pfw[rl * 128 + ((nb * 16 + ll) ^ ((lg & 1) << 4))] = cacc[nb][r];
      }
    float* co = ck ? ctx1 : ctx0;
#pragma unroll
    for (int ps = 0; ps < 4; ++ps) {
      const int row = ps * 4 + lg;
      const int cb = (ll * 4) ^ ((ps & 1) << 4);
      f32x4 cv = *(const f32x4*)&pfw[row * 128 + cb];
      *(f32x4*)&co[(size_t)(b * S_LEN + q0 + row) * DMODEL + h * 64 + ll * 4] = cv;
    }
  }

  // zero-fill masked columns inside this chunk (overwrite 0xAA poison)
  const int zs = ((qt + 1) * 64 > ktlo * 64) ? (qt + 1) * 64 : ktlo * 64;
  const int ze = (ktlo + 16) * 64;
  if (zs < ze) {
    f32x4 z = (f32x4){0.f, 0.f, 0.f, 0.f};
    for (int rr = 0; rr < 16; ++rr) {
      float* dst = pbase + (size_t)(q0 + rr) * S_LEN;
      for (int c = zs + l * 4; c < ze; c += 256)
        *(f32x4*)(dst + c) = z;
    }
  }
}

extern "C" void kernel_launch(void* const* d_in, const int* in_sizes, int n_in,
                              void* d_out, int out_size, void* d_ws, size_t ws_size,
                              hipStream_t stream) {
  const float* q_in = (const float*)d_in[0];
  const float* k_in = (const float*)d_in[1];
  const float* v_in = (const float*)d_in[2];
  // d_in[3] = mask: causal triu(k=1), hardcoded in attn kernels
  const float* wq = (const float*)d_in[4];
  const float* wk = (const float*)d_in[5];
  const float* wv = (const float*)d_in[6];
  const float* wo = (const float*)d_in[7];

  const int BSD = BATCH * S_LEN * DMODEL;  // 3145728
  const int DD = DMODEL * DMODEL;          // 589824
  const int M = BATCH * S_LEN;             // 4096

  char* ws = (char*)d_ws;
  unsigned short* qbf = (unsigned short*)ws;  ws += (size_t)BSD * 2;
  unsigned short* kbf = (unsigned short*)ws;  ws += (size_t)BSD * 2;
  unsigned short* vbf = (unsigned short*)ws;  ws += (size_t)BSD * 2;
  unsigned short* wqb = (unsigned short*)ws;  ws += (size_t)DD * 2;   // contiguous
  unsigned short* wkb = (unsigned short*)ws;  ws += (size_t)DD * 2;   //  W3 =
  unsigned short* wvb = (unsigned short*)ws;  ws += (size_t)DD * 2;   //  [2304][768]
  unsigned short* wob = (unsigned short*)ws;  ws += (size_t)DD * 2;
  unsigned short* Qs  = (unsigned short*)ws;  ws += (size_t)BSD * 2;
  unsigned short* Ks  = (unsigned short*)ws;  ws += (size_t)BSD * 2;
  unsigned short* VT  = (unsigned short*)ws;  ws += (size_t)BSD * 2;
  unsigned short* ctx = (unsigned short*)ws;  ws += (size_t)BSD * 2;
  float* ctx0 = (float*)ws;                   ws += (size_t)BSD * 4;
  float* ctx1 = (float*)ws;                   ws += (size_t)BSD * 4;
  float2* mlbuf = (float2*)ws;                ws += (size_t)M * NH * sizeof(float2);
  float2* mlpart = (float2*)ws;               ws += (size_t)M * NH * 4 * sizeof(float2);
  (void)wkb; (void)wvb;

  float* out_proj = (float*)d_out;
  float* attnw = (float*)d_out + BSD;

  cvt3_kernel<<<3 * N8_BSD / 256, 256, 0, stream>>>(q_in, k_in, v_in, qbf, ctx1);
  cvt4_kernel<<<4 * N8_DD / 256, 256, 0, stream>>>(wq, wk, wv, wo, wqb);

  gemm_qkv<<<dim3(M / 128, 2304 / 128), 256, 0, stream>>>(qbf, kbf, vbf, wqb,
                                                          Qs, Ks, VT);

  attn_mlp<<<80 * NH * BATCH, 256, 0, stream>>>(Qs, Ks, mlpart);
  ml_combine<<<M * NH / 256, 256, 0, stream>>>(mlpart, mlbuf);
  attn_p2<<<64 * NH * BATCH, 256, 0, stream>>>(Qs, Ks, VT, mlbuf, attnw,
                                               ctx0, ctx1);
  ctx_reduce<<<BSD / 4 / 256, 256, 0, stream>>>(ctx0, ctx1, ctx);

  gemm_proj<<<dim3(M / 128, DMODEL / 128), 256, 0, stream>>>(ctx, wob, out_proj);
}

// Round 11
// 218.399 us; speedup vs baseline: 1.2777x; 1.2612x over previous
//
#include <hip/hip_runtime.h>

#define BATCH 2
#define S_LEN 2048
#define NH 12
#define DMODEL 768
// DK = 64, scale = 1/8

#define N8_BSD (BATCH * S_LEN * DMODEL / 8)  // 393216
#define N8_DD (DMODEL * DMODEL / 8)          // 73728

typedef __attribute__((ext_vector_type(8))) short bf16x8;
typedef __attribute__((ext_vector_type(4))) float f32x4;
typedef __attribute__((ext_vector_type(4))) unsigned short us4;

__device__ __forceinline__ unsigned short f2bf(float f) {
  union { float f; unsigned int u; } v; v.f = f;
  unsigned int r = v.u + 0x7fffu + ((v.u >> 16) & 1u);  // RNE
  return (unsigned short)(r >> 16);
}

// ------- f32 -> bf16 converts (8 elems/thread); cvt3 also zeroes ctx1 -------
__global__ void cvt3_kernel(const float* __restrict__ s0,
                            const float* __restrict__ s1,
                            const float* __restrict__ s2,
                            unsigned short* __restrict__ dst,
                            float* __restrict__ ctx1) {
  int i = blockIdx.x * blockDim.x + threadIdx.x;  // 0 .. 3*N8_BSD-1 (exact)
  int j = i / N8_BSD;
  int k = i - j * N8_BSD;
  const float* s = (j == 0) ? s0 : (j == 1) ? s1 : s2;
  const float4* sp = (const float4*)s;
  float4 a = sp[k * 2], b = sp[k * 2 + 1];
  us4 o0 = { f2bf(a.x), f2bf(a.y), f2bf(a.z), f2bf(a.w) };
  us4 o1 = { f2bf(b.x), f2bf(b.y), f2bf(b.z), f2bf(b.w) };
  us4* d = (us4*)dst;
  d[i * 2] = o0;
  d[i * 2 + 1] = o1;
  if (j == 0) {  // zero ctx1 partial buffer (BSD f32 = exactly this segment)
    f32x4 z = (f32x4){0.f, 0.f, 0.f, 0.f};
    f32x4* c = (f32x4*)ctx1;
    c[k * 2] = z;
    c[k * 2 + 1] = z;
  }
}

__global__ void cvt4_kernel(const float* __restrict__ s0,
                            const float* __restrict__ s1,
                            const float* __restrict__ s2,
                            const float* __restrict__ s3,
                            unsigned short* __restrict__ dst) {
  int i = blockIdx.x * blockDim.x + threadIdx.x;  // 0 .. 4*N8_DD-1 (exact)
  int j = i / N8_DD;
  int k = i - j * N8_DD;
  const float* s = (j == 0) ? s0 : (j == 1) ? s1 : (j == 2) ? s2 : s3;
  const float4* sp = (const float4*)s;
  float4 a = sp[k * 2], b = sp[k * 2 + 1];
  us4 o0 = { f2bf(a.x), f2bf(a.y), f2bf(a.z), f2bf(a.w) };
  us4 o1 = { f2bf(b.x), f2bf(b.y), f2bf(b.z), f2bf(b.w) };
  us4* d = (us4*)dst;
  d[i * 2] = o0;
  d[i * 2 + 1] = o1;
}

// ------- reduce: ctx_bf16 = f2bf(ctx0 + ctx1), 4 elems/thread -------
__global__ void ctx_reduce(const float* __restrict__ c0,
                           const float* __restrict__ c1,
                           unsigned short* __restrict__ o) {
  int i = blockIdx.x * blockDim.x + threadIdx.x;  // 0 .. BSD/4-1
  float4 a = ((const float4*)c0)[i];
  float4 b = ((const float4*)c1)[i];
  us4 r = { f2bf(a.x + b.x), f2bf(a.y + b.y), f2bf(a.z + b.z), f2bf(a.w + b.w) };
  ((us4*)o)[i] = r;
}

#define GLD_LDS16(g, l)                                                    \
  __builtin_amdgcn_global_load_lds(                                        \
      (const __attribute__((address_space(1))) unsigned int*)(g),          \
      (__attribute__((address_space(3))) unsigned int*)(l), 16, 0, 0)

// ---------------- fused QKV projection GEMM, 128x128 tile ----------------
__global__ __launch_bounds__(256, 2)
void gemm_qkv(const unsigned short* __restrict__ Aq,
              const unsigned short* __restrict__ Ak,
              const unsigned short* __restrict__ Av,
              const unsigned short* __restrict__ W3,
              unsigned short* __restrict__ Qs,
              unsigned short* __restrict__ Ks,
              unsigned short* __restrict__ VT) {
  __shared__ unsigned short As[128 * 64];
  __shared__ unsigned short Bs[128 * 64];
  const int m0 = blockIdx.x * 128;
  const int n0g = blockIdx.y * 128;
  const int nblk = n0g / 768;         // 0=Q 1=K 2=V (uniform per block)
  const int n0 = n0g - nblk * 768;
  const unsigned short* A = (nblk == 0) ? Aq : (nblk == 1) ? Ak : Av;
  const unsigned short* Bw = W3 + (size_t)n0g * DMODEL;
  const int tid = threadIdx.x, w = tid >> 6, l = tid & 63;
  const int lg = l >> 4, ll = l & 15;
  const int wm = w >> 1, wn = w & 1;
  const int lr = l >> 3, lc = (l & 7) * 8;

  f32x4 acc[4][4];
#pragma unroll
  for (int i = 0; i < 4; ++i)
#pragma unroll
    for (int j = 0; j < 4; ++j) acc[i][j] = (f32x4){0.f, 0.f, 0.f, 0.f};

  for (int k0 = 0; k0 < DMODEL; k0 += 64) {
#pragma unroll
    for (int i = 0; i < 4; ++i) {
      GLD_LDS16(A + (size_t)(m0 + w * 32 + i * 8 + lr) * DMODEL + k0 + lc,
                &As[(w * 32 + i * 8) * 64]);
      GLD_LDS16(Bw + (size_t)(w * 32 + i * 8 + lr) * DMODEL + k0 + lc,
                &Bs[(w * 32 + i * 8) * 64]);
    }
    __syncthreads();
#pragma unroll
    for (int t = 0; t < 2; ++t) {
      bf16x8 af[4], bf[4];
#pragma unroll
      for (int mi = 0; mi < 4; ++mi)
        af[mi] = *(const bf16x8*)&As[(wm * 64 + mi * 16 + ll) * 64 + t * 32 + lg * 8];
#pragma unroll
      for (int ni = 0; ni < 4; ++ni)
        bf[ni] = *(const bf16x8*)&Bs[(wn * 64 + ni * 16 + ll) * 64 + t * 32 + lg * 8];
#pragma unroll
      for (int mi = 0; mi < 4; ++mi)
#pragma unroll
        for (int ni = 0; ni < 4; ++ni)
          acc[mi][ni] = __builtin_amdgcn_mfma_f32_16x16x32_bf16(
              af[mi], bf[ni], acc[mi][ni], 0, 0, 0);
    }
    __syncthreads();
  }

  if (nblk < 2) {  // Q or K: row-major [4096][768]; Q scaled by 1/8
    unsigned short* o = nblk ? Ks : Qs;
    const float sc = nblk ? 1.f : 0.125f;
#pragma unroll
    for (int mi = 0; mi < 4; ++mi)
#pragma unroll
      for (int ni = 0; ni < 4; ++ni) {
        const int col = n0 + wn * 64 + ni * 16 + ll;
        const int rowb = m0 + wm * 64 + mi * 16 + lg * 4;
#pragma unroll
        for (int r = 0; r < 4; ++r)
          o[(size_t)(rowb + r) * 768 + col] = f2bf(acc[mi][ni][r] * sc);
      }
  } else {  // V^T: (B,H,64,S)
#pragma unroll
    for (int mi = 0; mi < 4; ++mi)
#pragma unroll
      for (int ni = 0; ni < 4; ++ni) {
        const int col = n0 + wn * 64 + ni * 16 + ll;
        const int row = m0 + wm * 64 + mi * 16 + lg * 4;
        const int bb = row >> 11, sidx = row & (S_LEN - 1);
        const size_t base =
            ((size_t)(bb * NH + (col >> 6)) * 64 + (col & 63)) * S_LEN + sidx;
        us4 pk = { f2bf(acc[mi][ni][0]), f2bf(acc[mi][ni][1]),
                   f2bf(acc[mi][ni][2]), f2bf(acc[mi][ni][3]) };
        *(us4*)&VT[base] = pk;
      }
  }
}

// ---------------- output projection GEMM (f32 out), 128x128 tile ----------
__global__ __launch_bounds__(256, 2)
void gemm_proj(const unsigned short* __restrict__ A,
               const unsigned short* __restrict__ Bw,
               float* __restrict__ o) {
  __shared__ unsigned short As[128 * 64];
  __shared__ unsigned short Bs[128 * 64];
  const int m0 = blockIdx.x * 128, n0 = blockIdx.y * 128;
  const int tid = threadIdx.x, w = tid >> 6, l = tid & 63;
  const int lg = l >> 4, ll = l & 15;
  const int wm = w >> 1, wn = w & 1;
  const int lr = l >> 3, lc = (l & 7) * 8;

  f32x4 acc[4][4];
#pragma unroll
  for (int i = 0; i < 4; ++i)
#pragma unroll
    for (int j = 0; j < 4; ++j) acc[i][j] = (f32x4){0.f, 0.f, 0.f, 0.f};

  for (int k0 = 0; k0 < DMODEL; k0 += 64) {
#pragma unroll
    for (int i = 0; i < 4; ++i) {
      GLD_LDS16(A + (size_t)(m0 + w * 32 + i * 8 + lr) * DMODEL + k0 + lc,
                &As[(w * 32 + i * 8) * 64]);
      GLD_LDS16(Bw + (size_t)(n0 + w * 32 + i * 8 + lr) * DMODEL + k0 + lc,
                &Bs[(w * 32 + i * 8) * 64]);
    }
    __syncthreads();
#pragma unroll
    for (int t = 0; t < 2; ++t) {
      bf16x8 af[4], bf[4];
#pragma unroll
      for (int mi = 0; mi < 4; ++mi)
        af[mi] = *(const bf16x8*)&As[(wm * 64 + mi * 16 + ll) * 64 + t * 32 + lg * 8];
#pragma unroll
      for (int ni = 0; ni < 4; ++ni)
        bf[ni] = *(const bf16x8*)&Bs[(wn * 64 + ni * 16 + ll) * 64 + t * 32 + lg * 8];
#pragma unroll
      for (int mi = 0; mi < 4; ++mi)
#pragma unroll
        for (int ni = 0; ni < 4; ++ni)
          acc[mi][ni] = __builtin_amdgcn_mfma_f32_16x16x32_bf16(
              af[mi], bf[ni], acc[mi][ni], 0, 0, 0);
    }
    __syncthreads();
  }

#pragma unroll
  for (int mi = 0; mi < 4; ++mi)
#pragma unroll
    for (int ni = 0; ni < 4; ++ni) {
      const int col = n0 + wn * 64 + ni * 16 + ll;
      const int rowb = m0 + wm * 64 + mi * 16 + lg * 4;
#pragma unroll
      for (int r = 0; r < 4; ++r)
        o[(size_t)(rowb + r) * DMODEL + col] = acc[mi][ni][r];
    }
}

// Tile staging: 64x64 bf16 (8KB) via global_load_lds, LINEAR LDS dest with
// PRE-SWIZZLED global source (col16 ^= row&7) so ds_read_b128 fragment reads
// are bank-balanced. 256 threads, 2 issues/wave. LDS[row][c16] holds
// global[row][c16 ^ (row&7)].
#define STAGE_TILE(srcTile, srcStride, ldsT)                                  \
  {                                                                           \
    _Pragma("unroll") for (int j_ = 0; j_ < 2; ++j_) {                        \
      int slot_ = (j_ * 4 + w) * 64 + l;                                      \
      int row_ = slot_ >> 3, c16_ = slot_ & 7;                                \
      GLD_LDS16((srcTile) + (size_t)row_ * (srcStride) +                      \
                    ((c16_ ^ (row_ & 7)) << 3),                               \
                (ldsT) + (j_ * 4 + w) * 512);                                 \
    }                                                                         \
  }

// ---------------- attn pass 1: online (m, 1/l), LDS-staged K ----------------
// One WG per (q-tile, h, b); K tile staged ONCE per WG (4x read dedup),
// double-buffered, one barrier per tile.
__global__ __launch_bounds__(256, 3)
void attn_ml(const unsigned short* __restrict__ Qp,
             const unsigned short* __restrict__ Kp,
             float2* __restrict__ mlbuf) {
  const int idx = blockIdx.x;
  const int qt = 31 - idx / (NH * BATCH);  // heavy tiles first
  const int hb = idx % (NH * BATCH);
  const int h = hb >> 1, b = hb & 1;
  const int tid = threadIdx.x, w = tid >> 6, l = tid & 63;
  const int lg = l >> 4, ll = l & 15;
  __shared__ unsigned short Kt[2][64 * 64];

  const unsigned short* kbp = Kp + (size_t)b * S_LEN * DMODEL + h * 64;
  const int q0 = qt * 64 + w * 16;
  const int nkt = qt + 1;

  bf16x8 qf[2];
  {
    const unsigned short* qb =
        Qp + (size_t)(b * S_LEN + q0 + ll) * DMODEL + h * 64 + lg * 8;
    qf[0] = *(const bf16x8*)qb;
    qf[1] = *(const bf16x8*)(qb + 32);
  }
  int rowg[4];
#pragma unroll
  for (int r = 0; r < 4; ++r) rowg[r] = q0 + lg * 4 + r;

  float m[4], lsum[4];
#pragma unroll
  for (int r = 0; r < 4; ++r) { m[r] = -1e30f; lsum[r] = 0.f; }

  STAGE_TILE(kbp + (size_t)0 * 64 * DMODEL, DMODEL, &Kt[0][0]);
  __syncthreads();

  for (int kt = 0; kt < nkt; ++kt) {
    const int cur = kt & 1;
    if (kt + 1 < nkt)
      STAGE_TILE(kbp + (size_t)(kt + 1) * 64 * DMODEL, DMODEL, &Kt[cur ^ 1][0]);
    // fragments from LDS (swizzled read)
    bf16x8 kf[8];
#pragma unroll
    for (int t = 0; t < 2; ++t)
#pragma unroll
      for (int nb = 0; nb < 4; ++nb) {
        const int row = nb * 16 + ll;
        kf[t * 4 + nb] = *(const bf16x8*)&Kt[cur][row * 64 +
            (((t * 4 + lg) ^ (row & 7)) << 3)];
      }
    f32x4 sv[4];
#pragma unroll
    for (int nb = 0; nb < 4; ++nb) sv[nb] = (f32x4){0.f, 0.f, 0.f, 0.f};
#pragma unroll
    for (int t = 0; t < 2; ++t)
#pragma unroll
      for (int nb = 0; nb < 4; ++nb)
        sv[nb] = __builtin_amdgcn_mfma_f32_16x16x32_bf16(qf[t], kf[t * 4 + nb],
                                                         sv[nb], 0, 0, 0);
    if (kt == nkt - 1) {  // diagonal: causal mask
#pragma unroll
      for (int nb = 0; nb < 4; ++nb) {
        const int col = kt * 64 + nb * 16 + ll;
#pragma unroll
        for (int r = 0; r < 4; ++r)
          if (col > rowg[r]) sv[nb][r] = -1e30f;
      }
    }
#pragma unroll
    for (int r = 0; r < 4; ++r) {
      float tm = fmaxf(fmaxf(sv[0][r], sv[1][r]), fmaxf(sv[2][r], sv[3][r]));
      float mn = fmaxf(m[r], tm);
      float te = __expf(sv[0][r] - mn) + __expf(sv[1][r] - mn) +
                 __expf(sv[2][r] - mn) + __expf(sv[3][r] - mn);
      lsum[r] = lsum[r] * __expf(m[r] - mn) + te;
      m[r] = mn;
    }
    __syncthreads();  // staged tile ready; cur free for overwrite next iter
  }

  // butterfly combine across the 16 lanes sharing each row
#pragma unroll
  for (int off = 1; off < 16; off <<= 1)
#pragma unroll
    for (int r = 0; r < 4; ++r) {
      float om = __shfl_xor(m[r], off, 64);
      float ol = __shfl_xor(lsum[r], off, 64);
      float mn = fmaxf(m[r], om);
      lsum[r] = lsum[r] * __expf(m[r] - mn) + ol * __expf(om - mn);
      m[r] = mn;
    }

  if (ll == 0) {
    float2* mlb = mlbuf + (size_t)(b * NH + h) * S_LEN;
#pragma unroll
    for (int r = 0; r < 4; ++r)
      mlb[rowg[r]] = make_float2(m[r], 1.f / lsum[r]);
  }
}

// ---------------- attn pass 2: P write + PV, LDS-staged K and V ------------
// Grid: 64 slots x 24 (h,b), 16-tile chunks, heavy-first. K/V tiles staged
// once per WG (4x read dedup), double-buffered, one barrier per tile.
__global__ __launch_bounds__(256, 3)
void attn_p2(const unsigned short* __restrict__ Qp,
             const unsigned short* __restrict__ Kp,
             const unsigned short* __restrict__ VTp,
             const float2* __restrict__ mlbuf,
             float* __restrict__ attnw,
             float* __restrict__ ctx0,
             float* __restrict__ ctx1) {
  const int idx = blockIdx.x;
  const int slot = idx / (NH * BATCH);
  const int hb = idx % (NH * BATCH);
  const int h = hb >> 1, b = hb & 1;
  // slot -> (chunk, qt), sorted by value-tile count desc
  int qt, ck;
  if (slot <= 16)      { ck = 0; qt = 15 + slot; }
  else if (slot == 17) { ck = 1; qt = 31; }
  else if (slot < 48)  { int u = slot - 18; int k = 15 - (u >> 1);
                         if (u & 1) { ck = 1; qt = k + 15; } else { ck = 0; qt = k - 1; } }
  else                 { ck = 1; qt = slot - 48; }

  const int ktlo = ck * 16;
  const int kthi = (qt < ktlo + 15) ? qt : (ktlo + 15);  // last value tile
  const bool hasval = (ktlo <= qt);

  const int tid = threadIdx.x, w = tid >> 6, l = tid & 63;
  const int lg = l >> 4, ll = l & 15;
  __shared__ unsigned short Kt[2][64 * 64];  // 16KB
  __shared__ unsigned short Vt[2][64 * 64];  // 16KB
  __shared__ float pf32[4][1024];            // 16x64 f32 per wave (16KB)
  float* pfw = &pf32[w][0];

  const unsigned short* kbp = Kp + (size_t)b * S_LEN * DMODEL + h * 64;
  const unsigned short* vbp = VTp + ((size_t)(b * NH + h)) * 64 * S_LEN;
  float* pbase = attnw + ((size_t)(b * NH + h)) * S_LEN * S_LEN;

  const int q0 = qt * 64 + w * 16;
  int rowg[4];
#pragma unroll
  for (int r = 0; r < 4; ++r) rowg[r] = q0 + lg * 4 + r;

  if (hasval) {
    bf16x8 qf[2];
    {
      const unsigned short* qb =
          Qp + (size_t)(b * S_LEN + q0 + ll) * DMODEL + h * 64 + lg * 8;
      qf[0] = *(const bf16x8*)qb;
      qf[1] = *(const bf16x8*)(qb + 32);
    }
    float m[4], linv[4];
    {
      const float2* mlb = mlbuf + (size_t)(b * NH + h) * S_LEN;
#pragma unroll
      for (int r = 0; r < 4; ++r) {
        float2 t = mlb[rowg[r]];
        m[r] = t.x;
        linv[r] = t.y;
      }
    }

    f32x4 cacc[4];
#pragma unroll
    for (int nb = 0; nb < 4; ++nb) cacc[nb] = (f32x4){0.f, 0.f, 0.f, 0.f};

    STAGE_TILE(kbp + (size_t)ktlo * 64 * DMODEL, DMODEL, &Kt[0][0]);
    STAGE_TILE(vbp + (size_t)ktlo * 64, S_LEN, &Vt[0][0]);
    __syncthreads();

    for (int kt = ktlo; kt <= kthi; ++kt) {
      const int cur = (kt - ktlo) & 1;
      if (kt < kthi) {
        STAGE_TILE(kbp + (size_t)(kt + 1) * 64 * DMODEL, DMODEL, &Kt[cur ^ 1][0]);
        STAGE_TILE(vbp + (size_t)(kt + 1) * 64, S_LEN, &Vt[cur ^ 1][0]);
      }
      // K fragments from LDS + QK^T
      bf16x8 kf[8];
#pragma unroll
      for (int t = 0; t < 2; ++t)
#pragma unroll
        for (int nb = 0; nb < 4; ++nb) {
          const int row = nb * 16 + ll;
          kf[t * 4 + nb] = *(const bf16x8*)&Kt[cur][row * 64 +
              (((t * 4 + lg) ^ (row & 7)) << 3)];
        }
      f32x4 sv[4];
#pragma unroll
      for (int nb = 0; nb < 4; ++nb) sv[nb] = (f32x4){0.f, 0.f, 0.f, 0.f};
#pragma unroll
      for (int t = 0; t < 2; ++t)
#pragma unroll
        for (int nb = 0; nb < 4; ++nb)
          sv[nb] = __builtin_amdgcn_mfma_f32_16x16x32_bf16(qf[t], kf[t * 4 + nb],
                                                           sv[nb], 0, 0, 0);
      // p (masked -> exact 0) -> f32 LDS (wave-private; swz (lg&1)<<4)
#pragma unroll
      for (int nb = 0; nb < 4; ++nb) {
        const int col = kt * 64 + nb * 16 + ll;
#pragma unroll
        for (int r = 0; r < 4; ++r) {
          float p = (col <= rowg[r]) ? __expf(sv[nb][r] - m[r]) * linv[r] : 0.f;
          const int rl = lg * 4 + r;
          pfw[rl * 64 + ((nb * 16 + ll) ^ ((lg & 1) << 4))] = p;
        }
      }
      // PV A-frags: read f32 tile (row=ll) + cvt to bf16
      bf16x8 pf[2];
#pragma unroll
      for (int t = 0; t < 2; ++t) {
        const int c0 = (t * 32 + lg * 8) ^ (((ll >> 2) & 1) << 4);
        f32x4 lo = *(const f32x4*)&pfw[ll * 64 + c0];
        f32x4 hi = *(const f32x4*)&pfw[ll * 64 + c0 + 4];
        union { us4 hh[2]; bf16x8 v; } u;
        u.hh[0] = (us4){ f2bf(lo[0]), f2bf(lo[1]), f2bf(lo[2]), f2bf(lo[3]) };
        u.hh[1] = (us4){ f2bf(hi[0]), f2bf(hi[1]), f2bf(hi[2]), f2bf(hi[3]) };
        pf[t] = u.v;
      }
      // V fragments from LDS + PV
      bf16x8 vf[8];
#pragma unroll
      for (int t = 0; t < 2; ++t)
#pragma unroll
        for (int nb = 0; nb < 4; ++nb) {
          const int row = nb * 16 + ll;
          vf[t * 4 + nb] = *(const bf16x8*)&Vt[cur][row * 64 +
              (((t * 4 + lg) ^ (row & 7)) << 3)];
        }
#pragma unroll
      for (int t = 0; t < 2; ++t)
#pragma unroll
        for (int nb = 0; nb < 4; ++nb)
          cacc[nb] = __builtin_amdgcn_mfma_f32_16x16x32_bf16(
              pf[t], vf[t * 4 + nb], cacc[nb], 0, 0, 0);
      // coalesced P stores: 4 passes, each wave instr = 4 rows x 256B lines
#pragma unroll
      for (int ps = 0; ps < 4; ++ps) {
        const int row = ps * 4 + lg;                       // (row>>2)&1 == ps&1
        const int cb = (ll * 4) ^ ((ps & 1) << 4);
        f32x4 pv = *(const f32x4*)&pfw[row * 64 + cb];
        *(f32x4*)&pbase[(size_t)(q0 + row) * S_LEN + kt * 64 + ll * 4] = pv;
      }
      __syncthreads();  // staged next tile ready; cur free next iter
    }

    // PV partial -> ctx0/ctx1, coalesced via the wave-private f32 LDS tile
#pragma unroll
    for (int nb = 0; nb < 4; ++nb)
#pragma unroll
      for (int r = 0; r < 4; ++r) {
        const int rl = lg * 4 + r;
        pfw[rl * 64 + ((nb * 16 + ll) ^ ((lg & 1) << 4))] = cacc[nb][r];
      }
    float* co = ck ? ctx1 : ctx0;
#pragma unroll
    for (int ps = 0; ps < 4; ++ps) {
      const int row = ps * 4 + lg;
      const int cb = (ll * 4) ^ ((ps & 1) << 4);
      f32x4 cv = *(const f32x4*)&pfw[row * 64 + cb];
      *(f32x4*)&co[(size_t)(b * S_LEN + q0 + row) * DMODEL + h * 64 + ll * 4] = cv;
    }
  }

  // zero-fill masked columns inside this chunk (overwrite 0xAA poison)
  const int zs = ((qt + 1) * 64 > ktlo * 64) ? (qt + 1) * 64 : ktlo * 64;
  const int ze = (ktlo + 16) * 64;
  if (zs < ze) {
    f32x4 z = (f32x4){0.f, 0.f, 0.f, 0.f};
    for (int rr = 0; rr < 16; ++rr) {
      float* dst = pbase + (size_t)(q0 + rr) * S_LEN;
      for (int c = zs + l * 4; c < ze; c += 256)
        *(f32x4*)(dst + c) = z;
    }
  }
}

extern "C" void kernel_launch(void* const* d_in, const int* in_sizes, int n_in,
                              void* d_out, int out_size, void* d_ws, size_t ws_size,
                              hipStream_t stream) {
  const float* q_in = (const float*)d_in[0];
  const float* k_in = (const float*)d_in[1];
  const float* v_in = (const float*)d_in[2];
  // d_in[3] = mask: causal triu(k=1), hardcoded in attn kernels
  const float* wq = (const float*)d_in[4];
  const float* wk = (const float*)d_in[5];
  const float* wv = (const float*)d_in[6];
  const float* wo = (const float*)d_in[7];

  const int BSD = BATCH * S_LEN * DMODEL;  // 3145728
  const int DD = DMODEL * DMODEL;          // 589824
  const int M = BATCH * S_LEN;             // 4096

  char* ws = (char*)d_ws;
  unsigned short* qbf = (unsigned short*)ws;  ws += (size_t)BSD * 2;
  unsigned short* kbf = (unsigned short*)ws;  ws += (size_t)BSD * 2;
  unsigned short* vbf = (unsigned short*)ws;  ws += (size_t)BSD * 2;
  unsigned short* wqb = (unsigned short*)ws;  ws += (size_t)DD * 2;   // contiguous
  unsigned short* wkb = (unsigned short*)ws;  ws += (size_t)DD * 2;   //  W3 =
  unsigned short* wvb = (unsigned short*)ws;  ws += (size_t)DD * 2;   //  [2304][768]
  unsigned short* wob = (unsigned short*)ws;  ws += (size_t)DD * 2;
  unsigned short* Qs  = (unsigned short*)ws;  ws += (size_t)BSD * 2;
  unsigned short* Ks  = (unsigned short*)ws;  ws += (size_t)BSD * 2;
  unsigned short* VT  = (unsigned short*)ws;  ws += (size_t)BSD * 2;
  unsigned short* ctx = (unsigned short*)ws;  ws += (size_t)BSD * 2;
  float* ctx0 = (float*)ws;                   ws += (size_t)BSD * 4;
  float* ctx1 = (float*)ws;                   ws += (size_t)BSD * 4;
  float2* mlbuf = (float2*)ws;                ws += (size_t)M * NH * sizeof(float2);
  (void)wkb; (void)wvb;

  float* out_proj = (float*)d_out;
  float* attnw = (float*)d_out + BSD;

  cvt3_kernel<<<3 * N8_BSD / 256, 256, 0, stream>>>(q_in, k_in, v_in, qbf, ctx1);
  cvt4_kernel<<<4 * N8_DD / 256, 256, 0, stream>>>(wq, wk, wv, wo, wqb);

  gemm_qkv<<<dim3(M / 128, 2304 / 128), 256, 0, stream>>>(qbf, kbf, vbf, wqb,
                                                          Qs, Ks, VT);

  attn_ml<<<32 * NH * BATCH, 256, 0, stream>>>(Qs, Ks, mlbuf);
  attn_p2<<<64 * NH * BATCH, 256, 0, stream>>>(Qs, Ks, VT, mlbuf, attnw,
                                               ctx0, ctx1);
  ctx_reduce<<<BSD / 4 / 256, 256, 0, stream>>>(ctx0, ctx1, ctx);

  gemm_proj<<<dim3(M / 128, DMODEL / 128), 256, 0, stream>>>(ctx, wob, out_proj);
}

// Round 12
// 214.495 us; speedup vs baseline: 1.3009x; 1.0182x over previous
//
#include <hip/hip_runtime.h>

#define BATCH 2
#define S_LEN 2048
#define NH 12
#define DMODEL 768
// DK = 64, scale = 1/8

#define N8_BSD (BATCH * S_LEN * DMODEL / 8)  // 393216
#define N8_DD (DMODEL * DMODEL / 8)          // 73728

typedef __attribute__((ext_vector_type(8))) short bf16x8;
typedef __attribute__((ext_vector_type(4))) float f32x4;
typedef __attribute__((ext_vector_type(4))) unsigned short us4;

__device__ __forceinline__ unsigned short f2bf(float f) {
  union { float f; unsigned int u; } v; v.f = f;
  unsigned int r = v.u + 0x7fffu + ((v.u >> 16) & 1u);  // RNE
  return (unsigned short)(r >> 16);
}

// ------- f32 -> bf16 converts (8 elems/thread); cvt3 also zeroes ctx1 -------
__global__ void cvt3_kernel(const float* __restrict__ s0,
                            const float* __restrict__ s1,
                            const float* __restrict__ s2,
                            unsigned short* __restrict__ dst,
                            float* __restrict__ ctx1) {
  int i = blockIdx.x * blockDim.x + threadIdx.x;  // 0 .. 3*N8_BSD-1 (exact)
  int j = i / N8_BSD;
  int k = i - j * N8_BSD;
  const float* s = (j == 0) ? s0 : (j == 1) ? s1 : s2;
  const float4* sp = (const float4*)s;
  float4 a = sp[k * 2], b = sp[k * 2 + 1];
  us4 o0 = { f2bf(a.x), f2bf(a.y), f2bf(a.z), f2bf(a.w) };
  us4 o1 = { f2bf(b.x), f2bf(b.y), f2bf(b.z), f2bf(b.w) };
  us4* d = (us4*)dst;
  d[i * 2] = o0;
  d[i * 2 + 1] = o1;
  if (j == 0) {  // zero ctx1 partial buffer (BSD f32 = exactly this segment)
    f32x4 z = (f32x4){0.f, 0.f, 0.f, 0.f};
    f32x4* c = (f32x4*)ctx1;
    c[k * 2] = z;
    c[k * 2 + 1] = z;
  }
}

__global__ void cvt4_kernel(const float* __restrict__ s0,
                            const float* __restrict__ s1,
                            const float* __restrict__ s2,
                            const float* __restrict__ s3,
                            unsigned short* __restrict__ dst) {
  int i = blockIdx.x * blockDim.x + threadIdx.x;  // 0 .. 4*N8_DD-1 (exact)
  int j = i / N8_DD;
  int k = i - j * N8_DD;
  const float* s = (j == 0) ? s0 : (j == 1) ? s1 : (j == 2) ? s2 : s3;
  const float4* sp = (const float4*)s;
  float4 a = sp[k * 2], b = sp[k * 2 + 1];
  us4 o0 = { f2bf(a.x), f2bf(a.y), f2bf(a.z), f2bf(a.w) };
  us4 o1 = { f2bf(b.x), f2bf(b.y), f2bf(b.z), f2bf(b.w) };
  us4* d = (us4*)dst;
  d[i * 2] = o0;
  d[i * 2 + 1] = o1;
}

// ------- reduce: ctx_bf16 = f2bf(ctx0 + ctx1), 4 elems/thread -------
__global__ void ctx_reduce(const float* __restrict__ c0,
                           const float* __restrict__ c1,
                           unsigned short* __restrict__ o) {
  int i = blockIdx.x * blockDim.x + threadIdx.x;  // 0 .. BSD/4-1
  float4 a = ((const float4*)c0)[i];
  float4 b = ((const float4*)c1)[i];
  us4 r = { f2bf(a.x + b.x), f2bf(a.y + b.y), f2bf(a.z + b.z), f2bf(a.w + b.w) };
  ((us4*)o)[i] = r;
}

#define GLD_LDS16(g, l)                                                    \
  __builtin_amdgcn_global_load_lds(                                        \
      (const __attribute__((address_space(1))) unsigned int*)(g),          \
      (__attribute__((address_space(3))) unsigned int*)(l), 16, 0, 0)

// ---------------- fused QKV projection GEMM, 128x128 tile ----------------
__global__ __launch_bounds__(256, 2)
void gemm_qkv(const unsigned short* __restrict__ Aq,
              const unsigned short* __restrict__ Ak,
              const unsigned short* __restrict__ Av,
              const unsigned short* __restrict__ W3,
              unsigned short* __restrict__ Qs,
              unsigned short* __restrict__ Ks,
              unsigned short* __restrict__ VT) {
  __shared__ unsigned short As[128 * 64];
  __shared__ unsigned short Bs[128 * 64];
  const int m0 = blockIdx.x * 128;
  const int n0g = blockIdx.y * 128;
  const int nblk = n0g / 768;         // 0=Q 1=K 2=V (uniform per block)
  const int n0 = n0g - nblk * 768;
  const unsigned short* A = (nblk == 0) ? Aq : (nblk == 1) ? Ak : Av;
  const unsigned short* Bw = W3 + (size_t)n0g * DMODEL;
  const int tid = threadIdx.x, w = tid >> 6, l = tid & 63;
  const int lg = l >> 4, ll = l & 15;
  const int wm = w >> 1, wn = w & 1;
  const int lr = l >> 3, lc = (l & 7) * 8;

  f32x4 acc[4][4];
#pragma unroll
  for (int i = 0; i < 4; ++i)
#pragma unroll
    for (int j = 0; j < 4; ++j) acc[i][j] = (f32x4){0.f, 0.f, 0.f, 0.f};

  for (int k0 = 0; k0 < DMODEL; k0 += 64) {
#pragma unroll
    for (int i = 0; i < 4; ++i) {
      GLD_LDS16(A + (size_t)(m0 + w * 32 + i * 8 + lr) * DMODEL + k0 + lc,
                &As[(w * 32 + i * 8) * 64]);
      GLD_LDS16(Bw + (size_t)(w * 32 + i * 8 + lr) * DMODEL + k0 + lc,
                &Bs[(w * 32 + i * 8) * 64]);
    }
    __syncthreads();
#pragma unroll
    for (int t = 0; t < 2; ++t) {
      bf16x8 af[4], bf[4];
#pragma unroll
      for (int mi = 0; mi < 4; ++mi)
        af[mi] = *(const bf16x8*)&As[(wm * 64 + mi * 16 + ll) * 64 + t * 32 + lg * 8];
#pragma unroll
      for (int ni = 0; ni < 4; ++ni)
        bf[ni] = *(const bf16x8*)&Bs[(wn * 64 + ni * 16 + ll) * 64 + t * 32 + lg * 8];
#pragma unroll
      for (int mi = 0; mi < 4; ++mi)
#pragma unroll
        for (int ni = 0; ni < 4; ++ni)
          acc[mi][ni] = __builtin_amdgcn_mfma_f32_16x16x32_bf16(
              af[mi], bf[ni], acc[mi][ni], 0, 0, 0);
    }
    __syncthreads();
  }

  if (nblk < 2) {  // Q or K: row-major [4096][768]; Q scaled by 1/8
    unsigned short* o = nblk ? Ks : Qs;
    const float sc = nblk ? 1.f : 0.125f;
#pragma unroll
    for (int mi = 0; mi < 4; ++mi)
#pragma unroll
      for (int ni = 0; ni < 4; ++ni) {
        const int col = n0 + wn * 64 + ni * 16 + ll;
        const int rowb = m0 + wm * 64 + mi * 16 + lg * 4;
#pragma unroll
        for (int r = 0; r < 4; ++r)
          o[(size_t)(rowb + r) * 768 + col] = f2bf(acc[mi][ni][r] * sc);
      }
  } else {  // V^T: (B,H,64,S)
#pragma unroll
    for (int mi = 0; mi < 4; ++mi)
#pragma unroll
      for (int ni = 0; ni < 4; ++ni) {
        const int col = n0 + wn * 64 + ni * 16 + ll;
        const int row = m0 + wm * 64 + mi * 16 + lg * 4;
        const int bb = row >> 11, sidx = row & (S_LEN - 1);
        const size_t base =
            ((size_t)(bb * NH + (col >> 6)) * 64 + (col & 63)) * S_LEN + sidx;
        us4 pk = { f2bf(acc[mi][ni][0]), f2bf(acc[mi][ni][1]),
                   f2bf(acc[mi][ni][2]), f2bf(acc[mi][ni][3]) };
        *(us4*)&VT[base] = pk;
      }
  }
}

// ---------------- output projection GEMM (f32 out), 128x128 tile ----------
__global__ __launch_bounds__(256, 2)
void gemm_proj(const unsigned short* __restrict__ A,
               const unsigned short* __restrict__ Bw,
               float* __restrict__ o) {
  __shared__ unsigned short As[128 * 64];
  __shared__ unsigned short Bs[128 * 64];
  const int m0 = blockIdx.x * 128, n0 = blockIdx.y * 128;
  const int tid = threadIdx.x, w = tid >> 6, l = tid & 63;
  const int lg = l >> 4, ll = l & 15;
  const int wm = w >> 1, wn = w & 1;
  const int lr = l >> 3, lc = (l & 7) * 8;

  f32x4 acc[4][4];
#pragma unroll
  for (int i = 0; i < 4; ++i)
#pragma unroll
    for (int j = 0; j < 4; ++j) acc[i][j] = (f32x4){0.f, 0.f, 0.f, 0.f};

  for (int k0 = 0; k0 < DMODEL; k0 += 64) {
#pragma unroll
    for (int i = 0; i < 4; ++i) {
      GLD_LDS16(A + (size_t)(m0 + w * 32 + i * 8 + lr) * DMODEL + k0 + lc,
                &As[(w * 32 + i * 8) * 64]);
      GLD_LDS16(Bw + (size_t)(n0 + w * 32 + i * 8 + lr) * DMODEL + k0 + lc,
                &Bs[(w * 32 + i * 8) * 64]);
    }
    __syncthreads();
#pragma unroll
    for (int t = 0; t < 2; ++t) {
      bf16x8 af[4], bf[4];
#pragma unroll
      for (int mi = 0; mi < 4; ++mi)
        af[mi] = *(const bf16x8*)&As[(wm * 64 + mi * 16 + ll) * 64 + t * 32 + lg * 8];
#pragma unroll
      for (int ni = 0; ni < 4; ++ni)
        bf[ni] = *(const bf16x8*)&Bs[(wn * 64 + ni * 16 + ll) * 64 + t * 32 + lg * 8];
#pragma unroll
      for (int mi = 0; mi < 4; ++mi)
#pragma unroll
        for (int ni = 0; ni < 4; ++ni)
          acc[mi][ni] = __builtin_amdgcn_mfma_f32_16x16x32_bf16(
              af[mi], bf[ni], acc[mi][ni], 0, 0, 0);
    }
    __syncthreads();
  }

#pragma unroll
  for (int mi = 0; mi < 4; ++mi)
#pragma unroll
    for (int ni = 0; ni < 4; ++ni) {
      const int col = n0 + wn * 64 + ni * 16 + ll;
      const int rowb = m0 + wm * 64 + mi * 16 + lg * 4;
#pragma unroll
      for (int r = 0; r < 4; ++r)
        o[(size_t)(rowb + r) * DMODEL + col] = acc[mi][ni][r];
    }
}

// Tile staging: 64x64 bf16 (8KB) via global_load_lds, LINEAR LDS dest with
// PRE-SWIZZLED global source (col16 ^= row&7).
#define STAGE_TILE(srcTile, srcStride, ldsT)                                  \
  {                                                                           \
    _Pragma("unroll") for (int j_ = 0; j_ < 2; ++j_) {                        \
      int slot_ = (j_ * 4 + w) * 64 + l;                                      \
      int row_ = slot_ >> 3, c16_ = slot_ & 7;                                \
      GLD_LDS16((srcTile) + (size_t)row_ * (srcStride) +                      \
                    ((c16_ ^ (row_ & 7)) << 3),                               \
                (ldsT) + (j_ * 4 + w) * 512);                                 \
    }                                                                         \
  }

// ---------------- attn pass 1: online (m, 1/l), LDS-staged K ----------------
// One WG per (q-tile, h, b); K tile staged ONCE per WG (4x read dedup),
// double-buffered, one barrier per tile.  (R11 version, confirmed +52us.)
__global__ __launch_bounds__(256, 3)
void attn_ml(const unsigned short* __restrict__ Qp,
             const unsigned short* __restrict__ Kp,
             float2* __restrict__ mlbuf) {
  const int idx = blockIdx.x;
  const int qt = 31 - idx / (NH * BATCH);  // heavy tiles first
  const int hb = idx % (NH * BATCH);
  const int h = hb >> 1, b = hb & 1;
  const int tid = threadIdx.x, w = tid >> 6, l = tid & 63;
  const int lg = l >> 4, ll = l & 15;
  __shared__ unsigned short Kt[2][64 * 64];

  const unsigned short* kbp = Kp + (size_t)b * S_LEN * DMODEL + h * 64;
  const int q0 = qt * 64 + w * 16;
  const int nkt = qt + 1;

  bf16x8 qf[2];
  {
    const unsigned short* qb =
        Qp + (size_t)(b * S_LEN + q0 + ll) * DMODEL + h * 64 + lg * 8;
    qf[0] = *(const bf16x8*)qb;
    qf[1] = *(const bf16x8*)(qb + 32);
  }
  int rowg[4];
#pragma unroll
  for (int r = 0; r < 4; ++r) rowg[r] = q0 + lg * 4 + r;

  float m[4], lsum[4];
#pragma unroll
  for (int r = 0; r < 4; ++r) { m[r] = -1e30f; lsum[r] = 0.f; }

  STAGE_TILE(kbp + (size_t)0 * 64 * DMODEL, DMODEL, &Kt[0][0]);
  __syncthreads();

  for (int kt = 0; kt < nkt; ++kt) {
    const int cur = kt & 1;
    if (kt + 1 < nkt)
      STAGE_TILE(kbp + (size_t)(kt + 1) * 64 * DMODEL, DMODEL, &Kt[cur ^ 1][0]);
    bf16x8 kf[8];
#pragma unroll
    for (int t = 0; t < 2; ++t)
#pragma unroll
      for (int nb = 0; nb < 4; ++nb) {
        const int row = nb * 16 + ll;
        kf[t * 4 + nb] = *(const bf16x8*)&Kt[cur][row * 64 +
            (((t * 4 + lg) ^ (row & 7)) << 3)];
      }
    f32x4 sv[4];
#pragma unroll
    for (int nb = 0; nb < 4; ++nb) sv[nb] = (f32x4){0.f, 0.f, 0.f, 0.f};
#pragma unroll
    for (int t = 0; t < 2; ++t)
#pragma unroll
      for (int nb = 0; nb < 4; ++nb)
        sv[nb] = __builtin_amdgcn_mfma_f32_16x16x32_bf16(qf[t], kf[t * 4 + nb],
                                                         sv[nb], 0, 0, 0);
    if (kt == nkt - 1) {  // diagonal: causal mask
#pragma unroll
      for (int nb = 0; nb < 4; ++nb) {
        const int col = kt * 64 + nb * 16 + ll;
#pragma unroll
        for (int r = 0; r < 4; ++r)
          if (col > rowg[r]) sv[nb][r] = -1e30f;
      }
    }
#pragma unroll
    for (int r = 0; r < 4; ++r) {
      float tm = fmaxf(fmaxf(sv[0][r], sv[1][r]), fmaxf(sv[2][r], sv[3][r]));
      float mn = fmaxf(m[r], tm);
      float te = __expf(sv[0][r] - mn) + __expf(sv[1][r] - mn) +
                 __expf(sv[2][r] - mn) + __expf(sv[3][r] - mn);
      lsum[r] = lsum[r] * __expf(m[r] - mn) + te;
      m[r] = mn;
    }
    __syncthreads();
  }

#pragma unroll
  for (int off = 1; off < 16; off <<= 1)
#pragma unroll
    for (int r = 0; r < 4; ++r) {
      float om = __shfl_xor(m[r], off, 64);
      float ol = __shfl_xor(lsum[r], off, 64);
      float mn = fmaxf(m[r], om);
      lsum[r] = lsum[r] * __expf(m[r] - mn) + ol * __expf(om - mn);
      m[r] = mn;
    }

  if (ll == 0) {
    float2* mlb = mlbuf + (size_t)(b * NH + h) * S_LEN;
#pragma unroll
    for (int r = 0; r < 4; ++r)
      mlb[rowg[r]] = make_float2(m[r], 1.f / lsum[r]);
  }
}

// ---------------- attn pass 2: k-split waves, NO loop barriers --------------
// WG = (64 q-rows, 16-tile chunk). Wave w owns k-tiles {ktlo+w, +4, +8, +12}
// (DISJOINT -> zero read duplication, direct reg loads, no staging barriers).
// Per tile: QK (col-half split) -> exp -> wave-private 64x64 f32 LDS ->
// PV + full-line P stores. One barrier total for 4-way cacc reduce.
__global__ __launch_bounds__(256, 2)
void attn_p2(const unsigned short* __restrict__ Qp,
             const unsigned short* __restrict__ Kp,
             const unsigned short* __restrict__ VTp,
             const float2* __restrict__ mlbuf,
             float* __restrict__ attnw,
             float* __restrict__ ctx0,
             float* __restrict__ ctx1) {
  const int idx = blockIdx.x;
  const int slot = idx / (NH * BATCH);
  const int hb = idx % (NH * BATCH);
  const int h = hb >> 1, b = hb & 1;
  // slot -> (chunk, qt), sorted by value-tile count desc
  int qt, ck;
  if (slot <= 16)      { ck = 0; qt = 15 + slot; }
  else if (slot == 17) { ck = 1; qt = 31; }
  else if (slot < 48)  { int u = slot - 18; int k = 15 - (u >> 1);
                         if (u & 1) { ck = 1; qt = k + 15; } else { ck = 0; qt = k - 1; } }
  else                 { ck = 1; qt = slot - 48; }

  const int ktlo = ck * 16;
  const int kthi = (qt < ktlo + 15) ? qt : (ktlo + 15);  // last value tile
  const bool hasval = (ktlo <= qt);

  const int tid = threadIdx.x, w = tid >> 6, l = tid & 63;
  const int lg = l >> 4, ll = l & 15;
  __shared__ float pf32[4][64 * 64];  // 16KB per wave (private)
  float* pfw = &pf32[w][0];

  const unsigned short* kbp = Kp + (size_t)b * S_LEN * DMODEL + h * 64;
  const unsigned short* vbp = VTp + ((size_t)(b * NH + h)) * 64 * S_LEN;
  float* pbase = attnw + ((size_t)(b * NH + h)) * S_LEN * S_LEN;
  const int q0g = qt * 64;

  if (hasval) {
    // Q fragments for all 4 q-row-blocks (A-operand shared across k-tiles)
    bf16x8 qf[4][2];
#pragma unroll
    for (int rb = 0; rb < 4; ++rb) {
      const unsigned short* qb =
          Qp + (size_t)(b * S_LEN + q0g + rb * 16 + ll) * DMODEL + h * 64 + lg * 8;
      qf[rb][0] = *(const bf16x8*)qb;
      qf[rb][1] = *(const bf16x8*)(qb + 32);
    }
    float m16[4][4], li16[4][4];
    {
      const float2* mlb = mlbuf + (size_t)(b * NH + h) * S_LEN;
#pragma unroll
      for (int rb = 0; rb < 4; ++rb)
#pragma unroll
        for (int r = 0; r < 4; ++r) {
          float2 t = mlb[q0g + rb * 16 + lg * 4 + r];
          m16[rb][r] = t.x;
          li16[rb][r] = t.y;
        }
    }

    f32x4 cacc[4][4];  // [q-rowblock][v-dimblock]
#pragma unroll
    for (int rb = 0; rb < 4; ++rb)
#pragma unroll
      for (int vb = 0; vb < 4; ++vb) cacc[rb][vb] = (f32x4){0.f, 0.f, 0.f, 0.f};

    for (int kt = ktlo + w; kt <= kthi; kt += 4) {
      // ---- QK + exp, in two column halves (VGPR cap) ----
#pragma unroll
      for (int hh = 0; hh < 2; ++hh) {
        bf16x8 kf[2][2];  // [t][nbl]
#pragma unroll
        for (int t = 0; t < 2; ++t)
#pragma unroll
          for (int nbl = 0; nbl < 2; ++nbl) {
            const int nb = hh * 2 + nbl;
            kf[t][nbl] = *(const bf16x8*)(kbp +
                (size_t)(kt * 64 + nb * 16 + ll) * DMODEL + t * 32 + lg * 8);
          }
        f32x4 sv[4][2];
#pragma unroll
        for (int rb = 0; rb < 4; ++rb)
#pragma unroll
          for (int nbl = 0; nbl < 2; ++nbl) sv[rb][nbl] = (f32x4){0.f, 0.f, 0.f, 0.f};
#pragma unroll
        for (int t = 0; t < 2; ++t)
#pragma unroll
          for (int rb = 0; rb < 4; ++rb)
#pragma unroll
            for (int nbl = 0; nbl < 2; ++nbl)
              sv[rb][nbl] = __builtin_amdgcn_mfma_f32_16x16x32_bf16(
                  qf[rb][t], kf[t][nbl], sv[rb][nbl], 0, 0, 0);
        // exp + write to wave-private f32 LDS (swz (lg&1)<<4 == (row>>2)&1)
#pragma unroll
        for (int nbl = 0; nbl < 2; ++nbl) {
          const int nb = hh * 2 + nbl;
          const int col = kt * 64 + nb * 16 + ll;
#pragma unroll
          for (int rb = 0; rb < 4; ++rb)
#pragma unroll
            for (int r = 0; r < 4; ++r) {
              const int row = q0g + rb * 16 + lg * 4 + r;
              float p = (col <= row)
                            ? __expf(sv[rb][nbl][r] - m16[rb][r]) * li16[rb][r]
                            : 0.f;
              pfw[(rb * 16 + lg * 4 + r) * 64 +
                  ((nb * 16 + ll) ^ ((lg & 1) << 4))] = p;
            }
        }
      }
      // ---- PV: read P back per k-half, cvt to bf16, MFMA with V ----
#pragma unroll
      for (int t = 0; t < 2; ++t) {
        bf16x8 pfr[4];
#pragma unroll
        for (int rb = 0; rb < 4; ++rb) {
          const int row = rb * 16 + ll;
          const int c0 = (t * 32 + lg * 8) ^ (((ll >> 2) & 1) << 4);
          f32x4 lo = *(const f32x4*)&pfw[row * 64 + c0];
          f32x4 hi = *(const f32x4*)&pfw[row * 64 + c0 + 4];
          union { us4 hh2[2]; bf16x8 v; } u;
          u.hh2[0] = (us4){ f2bf(lo[0]), f2bf(lo[1]), f2bf(lo[2]), f2bf(lo[3]) };
          u.hh2[1] = (us4){ f2bf(hi[0]), f2bf(hi[1]), f2bf(hi[2]), f2bf(hi[3]) };
          pfr[rb] = u.v;
        }
        bf16x8 vf[4];
#pragma unroll
        for (int vb = 0; vb < 4; ++vb)
          vf[vb] = *(const bf16x8*)(vbp +
              (size_t)(vb * 16 + ll) * S_LEN + kt * 64 + t * 32 + lg * 8);
#pragma unroll
        for (int rb = 0; rb < 4; ++rb)
#pragma unroll
          for (int vb = 0; vb < 4; ++vb)
            cacc[rb][vb] = __builtin_amdgcn_mfma_f32_16x16x32_bf16(
                pfr[rb], vf[vb], cacc[rb][vb], 0, 0, 0);
      }
      // ---- P stores: 16 passes x (4 rows x 256B full lines) ----
#pragma unroll
      for (int ps = 0; ps < 16; ++ps) {
        const int row = ps * 4 + lg;  // (row>>2)&1 == ps&1
        const int cb = (ll * 4) ^ ((ps & 1) << 4);
        f32x4 pv = *(const f32x4*)&pfw[row * 64 + cb];
        *(f32x4*)&pbase[(size_t)(q0g + row) * S_LEN + kt * 64 + ll * 4] = pv;
      }
    }

    // ---- cacc 4-way reduce across waves (the only barrier) ----
#pragma unroll
    for (int rb = 0; rb < 4; ++rb)
#pragma unroll
      for (int vb = 0; vb < 4; ++vb)
#pragma unroll
        for (int r = 0; r < 4; ++r)
          pfw[(rb * 16 + lg * 4 + r) * 64 +
              ((vb * 16 + ll) ^ ((lg & 1) << 4))] = cacc[rb][vb][r];
    __syncthreads();
    float* co = ck ? ctx1 : ctx0;
#pragma unroll
    for (int ps2 = 0; ps2 < 4; ++ps2) {
      const int row = w * 16 + ps2 * 4 + lg;  // (row>>2)&1 == ps2&1
      const int cb = (ll * 4) ^ ((ps2 & 1) << 4);
      f32x4 s0 = *(const f32x4*)&pf32[0][row * 64 + cb];
      f32x4 s1 = *(const f32x4*)&pf32[1][row * 64 + cb];
      f32x4 s2 = *(const f32x4*)&pf32[2][row * 64 + cb];
      f32x4 s3 = *(const f32x4*)&pf32[3][row * 64 + cb];
      f32x4 sm = (s0 + s1) + (s2 + s3);
      *(f32x4*)&co[(size_t)(b * S_LEN + q0g + row) * DMODEL + h * 64 + ll * 4] = sm;
    }
  }

  // zero-fill masked columns inside this chunk (overwrite 0xAA poison)
  const int q0w = qt * 64 + w * 16;
  const int zs = ((qt + 1) * 64 > ktlo * 64) ? (qt + 1) * 64 : ktlo * 64;
  const int ze = (ktlo + 16) * 64;
  if (zs < ze) {
    f32x4 z = (f32x4){0.f, 0.f, 0.f, 0.f};
    for (int rr = 0; rr < 16; ++rr) {
      float* dst = pbase + (size_t)(q0w + rr) * S_LEN;
      for (int c = zs + l * 4; c < ze; c += 256)
        *(f32x4*)(dst + c) = z;
    }
  }
}

extern "C" void kernel_launch(void* const* d_in, const int* in_sizes, int n_in,
                              void* d_out, int out_size, void* d_ws, size_t ws_size,
                              hipStream_t stream) {
  const float* q_in = (const float*)d_in[0];
  const float* k_in = (const float*)d_in[1];
  const float* v_in = (const float*)d_in[2];
  // d_in[3] = mask: causal triu(k=1), hardcoded in attn kernels
  const float* wq = (const float*)d_in[4];
  const float* wk = (const float*)d_in[5];
  const float* wv = (const float*)d_in[6];
  const float* wo = (const float*)d_in[7];

  const int BSD = BATCH * S_LEN * DMODEL;  // 3145728
  const int DD = DMODEL * DMODEL;          // 589824
  const int M = BATCH * S_LEN;             // 4096

  char* ws = (char*)d_ws;
  unsigned short* qbf = (unsigned short*)ws;  ws += (size_t)BSD * 2;
  unsigned short* kbf = (unsigned short*)ws;  ws += (size_t)BSD * 2;
  unsigned short* vbf = (unsigned short*)ws;  ws += (size_t)BSD * 2;
  unsigned short* wqb = (unsigned short*)ws;  ws += (size_t)DD * 2;   // contiguous
  unsigned short* wkb = (unsigned short*)ws;  ws += (size_t)DD * 2;   //  W3 =
  unsigned short* wvb = (unsigned short*)ws;  ws += (size_t)DD * 2;   //  [2304][768]
  unsigned short* wob = (unsigned short*)ws;  ws += (size_t)DD * 2;
  unsigned short* Qs  = (unsigned short*)ws;  ws += (size_t)BSD * 2;
  unsigned short* Ks  = (unsigned short*)ws;  ws += (size_t)BSD * 2;
  unsigned short* VT  = (unsigned short*)ws;  ws += (size_t)BSD * 2;
  unsigned short* ctx = (unsigned short*)ws;  ws += (size_t)BSD * 2;
  float* ctx0 = (float*)ws;                   ws += (size_t)BSD * 4;
  float* ctx1 = (float*)ws;                   ws += (size_t)BSD * 4;
  float2* mlbuf = (float2*)ws;                ws += (size_t)M * NH * sizeof(float2);
  (void)wkb; (void)wvb;

  float* out_proj = (float*)d_out;
  float* attnw = (float*)d_out + BSD;

  cvt3_kernel<<<3 * N8_BSD / 256, 256, 0, stream>>>(q_in, k_in, v_in, qbf, ctx1);
  cvt4_kernel<<<4 * N8_DD / 256, 256, 0, stream>>>(wq, wk, wv, wo, wqb);

  gemm_qkv<<<dim3(M / 128, 2304 / 128), 256, 0, stream>>>(qbf, kbf, vbf, wqb,
                                                          Qs, Ks, VT);

  attn_ml<<<32 * NH * BATCH, 256, 0, stream>>>(Qs, Ks, mlbuf);
  attn_p2<<<64 * NH * BATCH, 256, 0, stream>>>(Qs, Ks, VT, mlbuf, attnw,
                                               ctx0, ctx1);
  ctx_reduce<<<BSD / 4 / 256, 256, 0, stream>>>(ctx0, ctx1, ctx);

  gemm_proj<<<dim3(M / 128, DMODEL / 128), 256, 0, stream>>>(ctx, wob, out_proj);
}

// Round 13
// 189.745 us; speedup vs baseline: 1.4706x; 1.1304x over previous
//
#include <hip/hip_runtime.h>

#define BATCH 2
#define S_LEN 2048
#define NH 12
#define DMODEL 768
// DK = 64, scale = 1/8

#define N8_BSD (BATCH * S_LEN * DMODEL / 8)  // 393216
#define N8_DD (DMODEL * DMODEL / 8)          // 73728

typedef __attribute__((ext_vector_type(8))) short bf16x8;
typedef __attribute__((ext_vector_type(4))) float f32x4;
typedef __attribute__((ext_vector_type(4))) unsigned short us4;

__device__ __forceinline__ unsigned short f2bf(float f) {
  union { float f; unsigned int u; } v; v.f = f;
  unsigned int r = v.u + 0x7fffu + ((v.u >> 16) & 1u);  // RNE
  return (unsigned short)(r >> 16);
}

// ------- f32 -> bf16 converts (8 elems/thread) -------
__global__ void cvt3_kernel(const float* __restrict__ s0,
                            const float* __restrict__ s1,
                            const float* __restrict__ s2,
                            unsigned short* __restrict__ dst) {
  int i = blockIdx.x * blockDim.x + threadIdx.x;  // 0 .. 3*N8_BSD-1 (exact)
  int j = i / N8_BSD;
  int k = i - j * N8_BSD;
  const float* s = (j == 0) ? s0 : (j == 1) ? s1 : s2;
  const float4* sp = (const float4*)s;
  float4 a = sp[k * 2], b = sp[k * 2 + 1];
  us4 o0 = { f2bf(a.x), f2bf(a.y), f2bf(a.z), f2bf(a.w) };
  us4 o1 = { f2bf(b.x), f2bf(b.y), f2bf(b.z), f2bf(b.w) };
  us4* d = (us4*)dst;
  d[i * 2] = o0;
  d[i * 2 + 1] = o1;
}

__global__ void cvt4_kernel(const float* __restrict__ s0,
                            const float* __restrict__ s1,
                            const float* __restrict__ s2,
                            const float* __restrict__ s3,
                            unsigned short* __restrict__ dst) {
  int i = blockIdx.x * blockDim.x + threadIdx.x;  // 0 .. 4*N8_DD-1 (exact)
  int j = i / N8_DD;
  int k = i - j * N8_DD;
  const float* s = (j == 0) ? s0 : (j == 1) ? s1 : (j == 2) ? s2 : s3;
  const float4* sp = (const float4*)s;
  float4 a = sp[k * 2], b = sp[k * 2 + 1];
  us4 o0 = { f2bf(a.x), f2bf(a.y), f2bf(a.z), f2bf(a.w) };
  us4 o1 = { f2bf(b.x), f2bf(b.y), f2bf(b.z), f2bf(b.w) };
  us4* d = (us4*)dst;
  d[i * 2] = o0;
  d[i * 2 + 1] = o1;
}

// ------- reduce: ctx_bf16 = f2bf(ctx0 [+ ctx1 if row>=1024]) -------
// ctx1 rows < 1024 (per batch) are never written by p2 chunk-1 -> skip read.
__global__ void ctx_reduce(const float* __restrict__ c0,
                           const float* __restrict__ c1,
                           unsigned short* __restrict__ o) {
  int i = blockIdx.x * blockDim.x + threadIdx.x;  // 0 .. BSD/4-1 (f32x4 units)
  int s = (i / 192) & (S_LEN - 1);  // 192 f32x4 per row (DMODEL=768)
  float4 a = ((const float4*)c0)[i];
  float4 r = a;
  if (s >= 1024) {
    float4 b = ((const float4*)c1)[i];
    r.x += b.x; r.y += b.y; r.z += b.z; r.w += b.w;
  }
  us4 u = { f2bf(r.x), f2bf(r.y), f2bf(r.z), f2bf(r.w) };
  ((us4*)o)[i] = u;
}

#define GLD_LDS16(g, l)                                                    \
  __builtin_amdgcn_global_load_lds(                                        \
      (const __attribute__((address_space(1))) unsigned int*)(g),          \
      (__attribute__((address_space(3))) unsigned int*)(l), 16, 0, 0)

// ---------------- fused QKV projection GEMM, 128x128 tile ----------------
__global__ __launch_bounds__(256, 2)
void gemm_qkv(const unsigned short* __restrict__ Aq,
              const unsigned short* __restrict__ Ak,
              const unsigned short* __restrict__ Av,
              const unsigned short* __restrict__ W3,
              unsigned short* __restrict__ Qs,
              unsigned short* __restrict__ Ks,
              unsigned short* __restrict__ VT) {
  __shared__ unsigned short As[128 * 64];
  __shared__ unsigned short Bs[128 * 64];
  const int m0 = blockIdx.x * 128;
  const int n0g = blockIdx.y * 128;
  const int nblk = n0g / 768;         // 0=Q 1=K 2=V (uniform per block)
  const int n0 = n0g - nblk * 768;
  const unsigned short* A = (nblk == 0) ? Aq : (nblk == 1) ? Ak : Av;
  const unsigned short* Bw = W3 + (size_t)n0g * DMODEL;
  const int tid = threadIdx.x, w = tid >> 6, l = tid & 63;
  const int lg = l >> 4, ll = l & 15;
  const int wm = w >> 1, wn = w & 1;
  const int lr = l >> 3, lc = (l & 7) * 8;

  f32x4 acc[4][4];
#pragma unroll
  for (int i = 0; i < 4; ++i)
#pragma unroll
    for (int j = 0; j < 4; ++j) acc[i][j] = (f32x4){0.f, 0.f, 0.f, 0.f};

  for (int k0 = 0; k0 < DMODEL; k0 += 64) {
#pragma unroll
    for (int i = 0; i < 4; ++i) {
      GLD_LDS16(A + (size_t)(m0 + w * 32 + i * 8 + lr) * DMODEL + k0 + lc,
                &As[(w * 32 + i * 8) * 64]);
      GLD_LDS16(Bw + (size_t)(w * 32 + i * 8 + lr) * DMODEL + k0 + lc,
                &Bs[(w * 32 + i * 8) * 64]);
    }
    __syncthreads();
#pragma unroll
    for (int t = 0; t < 2; ++t) {
      bf16x8 af[4], bf[4];
#pragma unroll
      for (int mi = 0; mi < 4; ++mi)
        af[mi] = *(const bf16x8*)&As[(wm * 64 + mi * 16 + ll) * 64 + t * 32 + lg * 8];
#pragma unroll
      for (int ni = 0; ni < 4; ++ni)
        bf[ni] = *(const bf16x8*)&Bs[(wn * 64 + ni * 16 + ll) * 64 + t * 32 + lg * 8];
#pragma unroll
      for (int mi = 0; mi < 4; ++mi)
#pragma unroll
        for (int ni = 0; ni < 4; ++ni)
          acc[mi][ni] = __builtin_amdgcn_mfma_f32_16x16x32_bf16(
              af[mi], bf[ni], acc[mi][ni], 0, 0, 0);
    }
    __syncthreads();
  }

  if (nblk < 2) {  // Q or K: row-major [4096][768]; Q scaled by 1/8
    unsigned short* o = nblk ? Ks : Qs;
    const float sc = nblk ? 1.f : 0.125f;
#pragma unroll
    for (int mi = 0; mi < 4; ++mi)
#pragma unroll
      for (int ni = 0; ni < 4; ++ni) {
        const int col = n0 + wn * 64 + ni * 16 + ll;
        const int rowb = m0 + wm * 64 + mi * 16 + lg * 4;
#pragma unroll
        for (int r = 0; r < 4; ++r)
          o[(size_t)(rowb + r) * 768 + col] = f2bf(acc[mi][ni][r] * sc);
      }
  } else {  // V^T: (B,H,64,S)
#pragma unroll
    for (int mi = 0; mi < 4; ++mi)
#pragma unroll
      for (int ni = 0; ni < 4; ++ni) {
        const int col = n0 + wn * 64 + ni * 16 + ll;
        const int row = m0 + wm * 64 + mi * 16 + lg * 4;
        const int bb = row >> 11, sidx = row & (S_LEN - 1);
        const size_t base =
            ((size_t)(bb * NH + (col >> 6)) * 64 + (col & 63)) * S_LEN + sidx;
        us4 pk = { f2bf(acc[mi][ni][0]), f2bf(acc[mi][ni][1]),
                   f2bf(acc[mi][ni][2]), f2bf(acc[mi][ni][3]) };
        *(us4*)&VT[base] = pk;
      }
  }
}

// ---------------- output projection GEMM (f32 out), 128x128 tile ----------
__global__ __launch_bounds__(256, 2)
void gemm_proj(const unsigned short* __restrict__ A,
               const unsigned short* __restrict__ Bw,
               float* __restrict__ o) {
  __shared__ unsigned short As[128 * 64];
  __shared__ unsigned short Bs[128 * 64];
  const int m0 = blockIdx.x * 128, n0 = blockIdx.y * 128;
  const int tid = threadIdx.x, w = tid >> 6, l = tid & 63;
  const int lg = l >> 4, ll = l & 15;
  const int wm = w >> 1, wn = w & 1;
  const int lr = l >> 3, lc = (l & 7) * 8;

  f32x4 acc[4][4];
#pragma unroll
  for (int i = 0; i < 4; ++i)
#pragma unroll
    for (int j = 0; j < 4; ++j) acc[i][j] = (f32x4){0.f, 0.f, 0.f, 0.f};

  for (int k0 = 0; k0 < DMODEL; k0 += 64) {
#pragma unroll
    for (int i = 0; i < 4; ++i) {
      GLD_LDS16(A + (size_t)(m0 + w * 32 + i * 8 + lr) * DMODEL + k0 + lc,
                &As[(w * 32 + i * 8) * 64]);
      GLD_LDS16(Bw + (size_t)(n0 + w * 32 + i * 8 + lr) * DMODEL + k0 + lc,
                &Bs[(w * 32 + i * 8) * 64]);
    }
    __syncthreads();
#pragma unroll
    for (int t = 0; t < 2; ++t) {
      bf16x8 af[4], bf[4];
#pragma unroll
      for (int mi = 0; mi < 4; ++mi)
        af[mi] = *(const bf16x8*)&As[(wm * 64 + mi * 16 + ll) * 64 + t * 32 + lg * 8];
#pragma unroll
      for (int ni = 0; ni < 4; ++ni)
        bf[ni] = *(const bf16x8*)&Bs[(wn * 64 + ni * 16 + ll) * 64 + t * 32 + lg * 8];
#pragma unroll
      for (int mi = 0; mi < 4; ++mi)
#pragma unroll
        for (int ni = 0; ni < 4; ++ni)
          acc[mi][ni] = __builtin_amdgcn_mfma_f32_16x16x32_bf16(
              af[mi], bf[ni], acc[mi][ni], 0, 0, 0);
    }
    __syncthreads();
  }

#pragma unroll
  for (int mi = 0; mi < 4; ++mi)
#pragma unroll
    for (int ni = 0; ni < 4; ++ni) {
      const int col = n0 + wn * 64 + ni * 16 + ll;
      const int rowb = m0 + wm * 64 + mi * 16 + lg * 4;
#pragma unroll
      for (int r = 0; r < 4; ++r)
        o[(size_t)(rowb + r) * DMODEL + col] = acc[mi][ni][r];
    }
}

// Tile staging: 64x64 bf16 (8KB) via global_load_lds, LINEAR LDS dest with
// PRE-SWIZZLED global source (col16 ^= row&7).
#define STAGE_TILE(srcTile, srcStride, ldsT)                                  \
  {                                                                           \
    _Pragma("unroll") for (int j_ = 0; j_ < 2; ++j_) {                        \
      int slot_ = (j_ * 4 + w) * 64 + l;                                      \
      int row_ = slot_ >> 3, c16_ = slot_ & 7;                                \
      GLD_LDS16((srcTile) + (size_t)row_ * (srcStride) +                      \
                    ((c16_ ^ (row_ & 7)) << 3),                               \
                (ldsT) + (j_ * 4 + w) * 512);                                 \
    }                                                                         \
  }

// ---------------- attn pass 1: online (m, 1/l), LDS-staged K ----------------
__global__ __launch_bounds__(256, 3)
void attn_ml(const unsigned short* __restrict__ Qp,
             const unsigned short* __restrict__ Kp,
             float2* __restrict__ mlbuf) {
  const int idx = blockIdx.x;
  const int qt = 31 - idx / (NH * BATCH);  // heavy tiles first
  const int hb = idx % (NH * BATCH);
  const int h = hb >> 1, b = hb & 1;
  const int tid = threadIdx.x, w = tid >> 6, l = tid & 63;
  const int lg = l >> 4, ll = l & 15;
  __shared__ unsigned short Kt[2][64 * 64];

  const unsigned short* kbp = Kp + (size_t)b * S_LEN * DMODEL + h * 64;
  const int q0 = qt * 64 + w * 16;
  const int nkt = qt + 1;

  bf16x8 qf[2];
  {
    const unsigned short* qb =
        Qp + (size_t)(b * S_LEN + q0 + ll) * DMODEL + h * 64 + lg * 8;
    qf[0] = *(const bf16x8*)qb;
    qf[1] = *(const bf16x8*)(qb + 32);
  }
  int rowg[4];
#pragma unroll
  for (int r = 0; r < 4; ++r) rowg[r] = q0 + lg * 4 + r;

  float m[4], lsum[4];
#pragma unroll
  for (int r = 0; r < 4; ++r) { m[r] = -1e30f; lsum[r] = 0.f; }

  STAGE_TILE(kbp + (size_t)0 * 64 * DMODEL, DMODEL, &Kt[0][0]);
  __syncthreads();

  for (int kt = 0; kt < nkt; ++kt) {
    const int cur = kt & 1;
    if (kt + 1 < nkt)
      STAGE_TILE(kbp + (size_t)(kt + 1) * 64 * DMODEL, DMODEL, &Kt[cur ^ 1][0]);
    bf16x8 kf[8];
#pragma unroll
    for (int t = 0; t < 2; ++t)
#pragma unroll
      for (int nb = 0; nb < 4; ++nb) {
        const int row = nb * 16 + ll;
        kf[t * 4 + nb] = *(const bf16x8*)&Kt[cur][row * 64 +
            (((t * 4 + lg) ^ (row & 7)) << 3)];
      }
    f32x4 sv[4];
#pragma unroll
    for (int nb = 0; nb < 4; ++nb) sv[nb] = (f32x4){0.f, 0.f, 0.f, 0.f};
#pragma unroll
    for (int t = 0; t < 2; ++t)
#pragma unroll
      for (int nb = 0; nb < 4; ++nb)
        sv[nb] = __builtin_amdgcn_mfma_f32_16x16x32_bf16(qf[t], kf[t * 4 + nb],
                                                         sv[nb], 0, 0, 0);
    if (kt == nkt - 1) {  // diagonal: causal mask
#pragma unroll
      for (int nb = 0; nb < 4; ++nb) {
        const int col = kt * 64 + nb * 16 + ll;
#pragma unroll
        for (int r = 0; r < 4; ++r)
          if (col > rowg[r]) sv[nb][r] = -1e30f;
      }
    }
#pragma unroll
    for (int r = 0; r < 4; ++r) {
      float tm = fmaxf(fmaxf(sv[0][r], sv[1][r]), fmaxf(sv[2][r], sv[3][r]));
      float mn = fmaxf(m[r], tm);
      float te = __expf(sv[0][r] - mn) + __expf(sv[1][r] - mn) +
                 __expf(sv[2][r] - mn) + __expf(sv[3][r] - mn);
      lsum[r] = lsum[r] * __expf(m[r] - mn) + te;
      m[r] = mn;
    }
    __syncthreads();
  }

#pragma unroll
  for (int off = 1; off < 16; off <<= 1)
#pragma unroll
    for (int r = 0; r < 4; ++r) {
      float om = __shfl_xor(m[r], off, 64);
      float ol = __shfl_xor(lsum[r], off, 64);
      float mn = fmaxf(m[r], om);
      lsum[r] = lsum[r] * __expf(m[r] - mn) + ol * __expf(om - mn);
      m[r] = mn;
    }

  if (ll == 0) {
    float2* mlb = mlbuf + (size_t)(b * NH + h) * S_LEN;
#pragma unroll
    for (int r = 0; r < 4; ++r)
      mlb[rowg[r]] = make_float2(m[r], 1.f / lsum[r]);
  }
}

// ---------------- attn pass 2: k-split waves, hb-major, NT stores ----------
// Grid: idx = hb*64 + slot (panel WGs temporally clustered -> K/V L2 reuse).
// Wave w owns disjoint k-tiles {ktlo+w, +4, +8, +12}; no loop barriers.
// P + zero-fill stores are NONTEMPORAL (no L2 allocate -> K/V stays cached).
__global__ __launch_bounds__(256, 2)
void attn_p2(const unsigned short* __restrict__ Qp,
             const unsigned short* __restrict__ Kp,
             const unsigned short* __restrict__ VTp,
             const float2* __restrict__ mlbuf,
             float* __restrict__ attnw,
             float* __restrict__ ctx0,
             float* __restrict__ ctx1) {
  const int idx = blockIdx.x;
  const int hb = idx >> 6;           // panel-major ordering
  const int slot = idx & 63;
  const int h = hb >> 1, b = hb & 1;
  // slot -> (chunk, qt), sorted by value-tile count desc
  int qt, ck;
  if (slot <= 16)      { ck = 0; qt = 15 + slot; }
  else if (slot == 17) { ck = 1; qt = 31; }
  else if (slot < 48)  { int u = slot - 18; int k = 15 - (u >> 1);
                         if (u & 1) { ck = 1; qt = k + 15; } else { ck = 0; qt = k - 1; } }
  else                 { ck = 1; qt = slot - 48; }

  const int ktlo = ck * 16;
  const int kthi = (qt < ktlo + 15) ? qt : (ktlo + 15);  // last value tile
  const bool hasval = (ktlo <= qt);

  const int tid = threadIdx.x, w = tid >> 6, l = tid & 63;
  const int lg = l >> 4, ll = l & 15;
  __shared__ float pf32[4][64 * 64];  // 16KB per wave (private)
  float* pfw = &pf32[w][0];

  const unsigned short* kbp = Kp + (size_t)b * S_LEN * DMODEL + h * 64;
  const unsigned short* vbp = VTp + ((size_t)(b * NH + h)) * 64 * S_LEN;
  float* pbase = attnw + ((size_t)(b * NH + h)) * S_LEN * S_LEN;
  const int q0g = qt * 64;

  if (hasval) {
    bf16x8 qf[4][2];
#pragma unroll
    for (int rb = 0; rb < 4; ++rb) {
      const unsigned short* qb =
          Qp + (size_t)(b * S_LEN + q0g + rb * 16 + ll) * DMODEL + h * 64 + lg * 8;
      qf[rb][0] = *(const bf16x8*)qb;
      qf[rb][1] = *(const bf16x8*)(qb + 32);
    }
    float m16[4][4], li16[4][4];
    {
      const float2* mlb = mlbuf + (size_t)(b * NH + h) * S_LEN;
#pragma unroll
      for (int rb = 0; rb < 4; ++rb)
#pragma unroll
        for (int r = 0; r < 4; ++r) {
          float2 t = mlb[q0g + rb * 16 + lg * 4 + r];
          m16[rb][r] = t.x;
          li16[rb][r] = t.y;
        }
    }

    f32x4 cacc[4][4];  // [q-rowblock][v-dimblock]
#pragma unroll
    for (int rb = 0; rb < 4; ++rb)
#pragma unroll
      for (int vb = 0; vb < 4; ++vb) cacc[rb][vb] = (f32x4){0.f, 0.f, 0.f, 0.f};

    for (int kt = ktlo + w; kt <= kthi; kt += 4) {
      // ---- QK + exp, in two column halves (VGPR cap) ----
#pragma unroll
      for (int hh = 0; hh < 2; ++hh) {
        bf16x8 kf[2][2];  // [t][nbl]
#pragma unroll
        for (int t = 0; t < 2; ++t)
#pragma unroll
          for (int nbl = 0; nbl < 2; ++nbl) {
            const int nb = hh * 2 + nbl;
            kf[t][nbl] = *(const bf16x8*)(kbp +
                (size_t)(kt * 64 + nb * 16 + ll) * DMODEL + t * 32 + lg * 8);
          }
        f32x4 sv[4][2];
#pragma unroll
        for (int rb = 0; rb < 4; ++rb)
#pragma unroll
          for (int nbl = 0; nbl < 2; ++nbl) sv[rb][nbl] = (f32x4){0.f, 0.f, 0.f, 0.f};
#pragma unroll
        for (int t = 0; t < 2; ++t)
#pragma unroll
          for (int rb = 0; rb < 4; ++rb)
#pragma unroll
            for (int nbl = 0; nbl < 2; ++nbl)
              sv[rb][nbl] = __builtin_amdgcn_mfma_f32_16x16x32_bf16(
                  qf[rb][t], kf[t][nbl], sv[rb][nbl], 0, 0, 0);
#pragma unroll
        for (int nbl = 0; nbl < 2; ++nbl) {
          const int nb = hh * 2 + nbl;
          const int col = kt * 64 + nb * 16 + ll;
#pragma unroll
          for (int rb = 0; rb < 4; ++rb)
#pragma unroll
            for (int r = 0; r < 4; ++r) {
              const int row = q0g + rb * 16 + lg * 4 + r;
              float p = (col <= row)
                            ? __expf(sv[rb][nbl][r] - m16[rb][r]) * li16[rb][r]
                            : 0.f;
              pfw[(rb * 16 + lg * 4 + r) * 64 +
                  ((nb * 16 + ll) ^ ((lg & 1) << 4))] = p;
            }
        }
      }
      // ---- PV: read P back per k-half, cvt to bf16, MFMA with V ----
#pragma unroll
      for (int t = 0; t < 2; ++t) {
        bf16x8 pfr[4];
#pragma unroll
        for (int rb = 0; rb < 4; ++rb) {
          const int row = rb * 16 + ll;
          const int c0 = (t * 32 + lg * 8) ^ (((ll >> 2) & 1) << 4);
          f32x4 lo = *(const f32x4*)&pfw[row * 64 + c0];
          f32x4 hi = *(const f32x4*)&pfw[row * 64 + c0 + 4];
          union { us4 hh2[2]; bf16x8 v; } u;
          u.hh2[0] = (us4){ f2bf(lo[0]), f2bf(lo[1]), f2bf(lo[2]), f2bf(lo[3]) };
          u.hh2[1] = (us4){ f2bf(hi[0]), f2bf(hi[1]), f2bf(hi[2]), f2bf(hi[3]) };
          pfr[rb] = u.v;
        }
        bf16x8 vf[4];
#pragma unroll
        for (int vb = 0; vb < 4; ++vb)
          vf[vb] = *(const bf16x8*)(vbp +
              (size_t)(vb * 16 + ll) * S_LEN + kt * 64 + t * 32 + lg * 8);
#pragma unroll
        for (int rb = 0; rb < 4; ++rb)
#pragma unroll
          for (int vb = 0; vb < 4; ++vb)
            cacc[rb][vb] = __builtin_amdgcn_mfma_f32_16x16x32_bf16(
                pfr[rb], vf[vb], cacc[rb][vb], 0, 0, 0);
      }
      // ---- P stores: nontemporal, 16 passes x (4 rows x 256B lines) ----
#pragma unroll
      for (int ps = 0; ps < 16; ++ps) {
        const int row = ps * 4 + lg;  // (row>>2)&1 == ps&1
        const int cb = (ll * 4) ^ ((ps & 1) << 4);
        f32x4 pv = *(const f32x4*)&pfw[row * 64 + cb];
        __builtin_nontemporal_store(
            pv, (f32x4*)&pbase[(size_t)(q0g + row) * S_LEN + kt * 64 + ll * 4]);
      }
    }

    // ---- cacc 4-way reduce across waves (the only barrier) ----
#pragma unroll
    for (int rb = 0; rb < 4; ++rb)
#pragma unroll
      for (int vb = 0; vb < 4; ++vb)
#pragma unroll
        for (int r = 0; r < 4; ++r)
          pfw[(rb * 16 + lg * 4 + r) * 64 +
              ((vb * 16 + ll) ^ ((lg & 1) << 4))] = cacc[rb][vb][r];
    __syncthreads();
    float* co = ck ? ctx1 : ctx0;
#pragma unroll
    for (int ps2 = 0; ps2 < 4; ++ps2) {
      const int row = w * 16 + ps2 * 4 + lg;  // (row>>2)&1 == ps2&1
      const int cb = (ll * 4) ^ ((ps2 & 1) << 4);
      f32x4 s0 = *(const f32x4*)&pf32[0][row * 64 + cb];
      f32x4 s1 = *(const f32x4*)&pf32[1][row * 64 + cb];
      f32x4 s2 = *(const f32x4*)&pf32[2][row * 64 + cb];
      f32x4 s3 = *(const f32x4*)&pf32[3][row * 64 + cb];
      f32x4 sm = (s0 + s1) + (s2 + s3);
      *(f32x4*)&co[(size_t)(b * S_LEN + q0g + row) * DMODEL + h * 64 + ll * 4] = sm;
    }
  }

  // zero-fill masked columns inside this chunk (overwrite 0xAA poison)
  const int q0w = qt * 64 + w * 16;
  const int zs = ((qt + 1) * 64 > ktlo * 64) ? (qt + 1) * 64 : ktlo * 64;
  const int ze = (ktlo + 16) * 64;
  if (zs < ze) {
    f32x4 z = (f32x4){0.f, 0.f, 0.f, 0.f};
    for (int rr = 0; rr < 16; ++rr) {
      float* dst = pbase + (size_t)(q0w + rr) * S_LEN;
      for (int c = zs + l * 4; c < ze; c += 256)
        __builtin_nontemporal_store(z, (f32x4*)(dst + c));
    }
  }
}

extern "C" void kernel_launch(void* const* d_in, const int* in_sizes, int n_in,
                              void* d_out, int out_size, void* d_ws, size_t ws_size,
                              hipStream_t stream) {
  const float* q_in = (const float*)d_in[0];
  const float* k_in = (const float*)d_in[1];
  const float* v_in = (const float*)d_in[2];
  // d_in[3] = mask: causal triu(k=1), hardcoded in attn kernels
  const float* wq = (const float*)d_in[4];
  const float* wk = (const float*)d_in[5];
  const float* wv = (const float*)d_in[6];
  const float* wo = (const float*)d_in[7];

  const int BSD = BATCH * S_LEN * DMODEL;  // 3145728
  const int DD = DMODEL * DMODEL;          // 589824
  const int M = BATCH * S_LEN;             // 4096

  char* ws = (char*)d_ws;
  unsigned short* qbf = (unsigned short*)ws;  ws += (size_t)BSD * 2;
  unsigned short* kbf = (unsigned short*)ws;  ws += (size_t)BSD * 2;
  unsigned short* vbf = (unsigned short*)ws;  ws += (size_t)BSD * 2;
  unsigned short* wqb = (unsigned short*)ws;  ws += (size_t)DD * 2;   // contiguous
  unsigned short* wkb = (unsigned short*)ws;  ws += (size_t)DD * 2;   //  W3 =
  unsigned short* wvb = (unsigned short*)ws;  ws += (size_t)DD * 2;   //  [2304][768]
  unsigned short* wob = (unsigned short*)ws;  ws += (size_t)DD * 2;
  unsigned short* Qs  = (unsigned short*)ws;  ws += (size_t)BSD * 2;
  unsigned short* Ks  = (unsigned short*)ws;  ws += (size_t)BSD * 2;
  unsigned short* VT  = (unsigned short*)ws;  ws += (size_t)BSD * 2;
  unsigned short* ctx = (unsigned short*)ws;  ws += (size_t)BSD * 2;
  float* ctx0 = (float*)ws;                   ws += (size_t)BSD * 4;
  float* ctx1 = (float*)ws;                   ws += (size_t)BSD * 4;
  float2* mlbuf = (float2*)ws;                ws += (size_t)M * NH * sizeof(float2);
  (void)wkb; (void)wvb;

  float* out_proj = (float*)d_out;
  float* attnw = (float*)d_out + BSD;

  cvt3_kernel<<<3 * N8_BSD / 256, 256, 0, stream>>>(q_in, k_in, v_in, qbf);
  cvt4_kernel<<<4 * N8_DD / 256, 256, 0, stream>>>(wq, wk, wv, wo, wqb);

  gemm_qkv<<<dim3(M / 128, 2304 / 128), 256, 0, stream>>>(qbf, kbf, vbf, wqb,
                                                          Qs, Ks, VT);

  attn_ml<<<32 * NH * BATCH, 256, 0, stream>>>(Qs, Ks, mlbuf);
  attn_p2<<<64 * NH * BATCH, 256, 0, stream>>>(Qs, Ks, VT, mlbuf, attnw,
                                               ctx0, ctx1);
  ctx_reduce<<<BSD / 4 / 256, 256, 0, stream>>>(ctx0, ctx1, ctx);

  gemm_proj<<<dim3(M / 128, DMODEL / 128), 256, 0, stream>>>(ctx, wob, out_proj);
}

// Round 14
// 187.166 us; speedup vs baseline: 1.4909x; 1.0138x over previous
//
#include <hip/hip_runtime.h>

#define BATCH 2
#define S_LEN 2048
#define NH 12
#define DMODEL 768
// DK = 64, scale = 1/8

#define N8_BSD (BATCH * S_LEN * DMODEL / 8)  // 393216
#define N8_DD (DMODEL * DMODEL / 8)          // 73728

typedef __attribute__((ext_vector_type(8))) short bf16x8;
typedef __attribute__((ext_vector_type(4))) float f32x4;
typedef __attribute__((ext_vector_type(4))) unsigned short us4;

__device__ __forceinline__ unsigned short f2bf(float f) {
  union { float f; unsigned int u; } v; v.f = f;
  unsigned int r = v.u + 0x7fffu + ((v.u >> 16) & 1u);  // RNE
  return (unsigned short)(r >> 16);
}

// ------- f32 -> bf16 converts (8 elems/thread) -------
__global__ void cvt3_kernel(const float* __restrict__ s0,
                            const float* __restrict__ s1,
                            const float* __restrict__ s2,
                            unsigned short* __restrict__ dst) {
  int i = blockIdx.x * blockDim.x + threadIdx.x;  // 0 .. 3*N8_BSD-1 (exact)
  int j = i / N8_BSD;
  int k = i - j * N8_BSD;
  const float* s = (j == 0) ? s0 : (j == 1) ? s1 : s2;
  const float4* sp = (const float4*)s;
  float4 a = sp[k * 2], b = sp[k * 2 + 1];
  us4 o0 = { f2bf(a.x), f2bf(a.y), f2bf(a.z), f2bf(a.w) };
  us4 o1 = { f2bf(b.x), f2bf(b.y), f2bf(b.z), f2bf(b.w) };
  us4* d = (us4*)dst;
  d[i * 2] = o0;
  d[i * 2 + 1] = o1;
}

__global__ void cvt4_kernel(const float* __restrict__ s0,
                            const float* __restrict__ s1,
                            const float* __restrict__ s2,
                            const float* __restrict__ s3,
                            unsigned short* __restrict__ dst) {
  int i = blockIdx.x * blockDim.x + threadIdx.x;  // 0 .. 4*N8_DD-1 (exact)
  int j = i / N8_DD;
  int k = i - j * N8_DD;
  const float* s = (j == 0) ? s0 : (j == 1) ? s1 : (j == 2) ? s2 : s3;
  const float4* sp = (const float4*)s;
  float4 a = sp[k * 2], b = sp[k * 2 + 1];
  us4 o0 = { f2bf(a.x), f2bf(a.y), f2bf(a.z), f2bf(a.w) };
  us4 o1 = { f2bf(b.x), f2bf(b.y), f2bf(b.z), f2bf(b.w) };
  us4* d = (us4*)dst;
  d[i * 2] = o0;
  d[i * 2 + 1] = o1;
}

// ------- reduce: ctx_bf16 = f2bf(ctx0 [+ ctx1 if row>=1024]) -------
__global__ void ctx_reduce(const float* __restrict__ c0,
                           const float* __restrict__ c1,
                           unsigned short* __restrict__ o) {
  int i = blockIdx.x * blockDim.x + threadIdx.x;  // 0 .. BSD/4-1 (f32x4 units)
  int s = (i / 192) & (S_LEN - 1);  // 192 f32x4 per row (DMODEL=768)
  float4 a = ((const float4*)c0)[i];
  float4 r = a;
  if (s >= 1024) {
    float4 b = ((const float4*)c1)[i];
    r.x += b.x; r.y += b.y; r.z += b.z; r.w += b.w;
  }
  us4 u = { f2bf(r.x), f2bf(r.y), f2bf(r.z), f2bf(r.w) };
  ((us4*)o)[i] = u;
}

#define GLD_LDS16(g, l)                                                    \
  __builtin_amdgcn_global_load_lds(                                        \
      (const __attribute__((address_space(1))) unsigned int*)(g),          \
      (__attribute__((address_space(3))) unsigned int*)(l), 16, 0, 0)

// ---------------- fused QKV projection GEMM, 128x128 tile ----------------
__global__ __launch_bounds__(256, 2)
void gemm_qkv(const unsigned short* __restrict__ Aq,
              const unsigned short* __restrict__ Ak,
              const unsigned short* __restrict__ Av,
              const unsigned short* __restrict__ W3,
              unsigned short* __restrict__ Qs,
              unsigned short* __restrict__ Ks,
              unsigned short* __restrict__ VT) {
  __shared__ unsigned short As[128 * 64];
  __shared__ unsigned short Bs[128 * 64];
  const int m0 = blockIdx.x * 128;
  const int n0g = blockIdx.y * 128;
  const int nblk = n0g / 768;         // 0=Q 1=K 2=V (uniform per block)
  const int n0 = n0g - nblk * 768;
  const unsigned short* A = (nblk == 0) ? Aq : (nblk == 1) ? Ak : Av;
  const unsigned short* Bw = W3 + (size_t)n0g * DMODEL;
  const int tid = threadIdx.x, w = tid >> 6, l = tid & 63;
  const int lg = l >> 4, ll = l & 15;
  const int wm = w >> 1, wn = w & 1;
  const int lr = l >> 3, lc = (l & 7) * 8;

  f32x4 acc[4][4];
#pragma unroll
  for (int i = 0; i < 4; ++i)
#pragma unroll
    for (int j = 0; j < 4; ++j) acc[i][j] = (f32x4){0.f, 0.f, 0.f, 0.f};

  for (int k0 = 0; k0 < DMODEL; k0 += 64) {
#pragma unroll
    for (int i = 0; i < 4; ++i) {
      GLD_LDS16(A + (size_t)(m0 + w * 32 + i * 8 + lr) * DMODEL + k0 + lc,
                &As[(w * 32 + i * 8) * 64]);
      GLD_LDS16(Bw + (size_t)(w * 32 + i * 8 + lr) * DMODEL + k0 + lc,
                &Bs[(w * 32 + i * 8) * 64]);
    }
    __syncthreads();
#pragma unroll
    for (int t = 0; t < 2; ++t) {
      bf16x8 af[4], bf[4];
#pragma unroll
      for (int mi = 0; mi < 4; ++mi)
        af[mi] = *(const bf16x8*)&As[(wm * 64 + mi * 16 + ll) * 64 + t * 32 + lg * 8];
#pragma unroll
      for (int ni = 0; ni < 4; ++ni)
        bf[ni] = *(const bf16x8*)&Bs[(wn * 64 + ni * 16 + ll) * 64 + t * 32 + lg * 8];
#pragma unroll
      for (int mi = 0; mi < 4; ++mi)
#pragma unroll
        for (int ni = 0; ni < 4; ++ni)
          acc[mi][ni] = __builtin_amdgcn_mfma_f32_16x16x32_bf16(
              af[mi], bf[ni], acc[mi][ni], 0, 0, 0);
    }
    __syncthreads();
  }

  if (nblk < 2) {  // Q or K: row-major [4096][768]; Q scaled by 1/8
    unsigned short* o = nblk ? Ks : Qs;
    const float sc = nblk ? 1.f : 0.125f;
#pragma unroll
    for (int mi = 0; mi < 4; ++mi)
#pragma unroll
      for (int ni = 0; ni < 4; ++ni) {
        const int col = n0 + wn * 64 + ni * 16 + ll;
        const int rowb = m0 + wm * 64 + mi * 16 + lg * 4;
#pragma unroll
        for (int r = 0; r < 4; ++r)
          o[(size_t)(rowb + r) * 768 + col] = f2bf(acc[mi][ni][r] * sc);
      }
  } else {  // V^T: (B,H,64,S)
#pragma unroll
    for (int mi = 0; mi < 4; ++mi)
#pragma unroll
      for (int ni = 0; ni < 4; ++ni) {
        const int col = n0 + wn * 64 + ni * 16 + ll;
        const int row = m0 + wm * 64 + mi * 16 + lg * 4;
        const int bb = row >> 11, sidx = row & (S_LEN - 1);
        const size_t base =
            ((size_t)(bb * NH + (col >> 6)) * 64 + (col & 63)) * S_LEN + sidx;
        us4 pk = { f2bf(acc[mi][ni][0]), f2bf(acc[mi][ni][1]),
                   f2bf(acc[mi][ni][2]), f2bf(acc[mi][ni][3]) };
        *(us4*)&VT[base] = pk;
      }
  }
}

// ---------------- output projection GEMM (f32 out), 128x128 tile ----------
__global__ __launch_bounds__(256, 2)
void gemm_proj(const unsigned short* __restrict__ A,
               const unsigned short* __restrict__ Bw,
               float* __restrict__ o) {
  __shared__ unsigned short As[128 * 64];
  __shared__ unsigned short Bs[128 * 64];
  const int m0 = blockIdx.x * 128, n0 = blockIdx.y * 128;
  const int tid = threadIdx.x, w = tid >> 6, l = tid & 63;
  const int lg = l >> 4, ll = l & 15;
  const int wm = w >> 1, wn = w & 1;
  const int lr = l >> 3, lc = (l & 7) * 8;

  f32x4 acc[4][4];
#pragma unroll
  for (int i = 0; i < 4; ++i)
#pragma unroll
    for (int j = 0; j < 4; ++j) acc[i][j] = (f32x4){0.f, 0.f, 0.f, 0.f};

  for (int k0 = 0; k0 < DMODEL; k0 += 64) {
#pragma unroll
    for (int i = 0; i < 4; ++i) {
      GLD_LDS16(A + (size_t)(m0 + w * 32 + i * 8 + lr) * DMODEL + k0 + lc,
                &As[(w * 32 + i * 8) * 64]);
      GLD_LDS16(Bw + (size_t)(n0 + w * 32 + i * 8 + lr) * DMODEL + k0 + lc,
                &Bs[(w * 32 + i * 8) * 64]);
    }
    __syncthreads();
#pragma unroll
    for (int t = 0; t < 2; ++t) {
      bf16x8 af[4], bf[4];
#pragma unroll
      for (int mi = 0; mi < 4; ++mi)
        af[mi] = *(const bf16x8*)&As[(wm * 64 + mi * 16 + ll) * 64 + t * 32 + lg * 8];
#pragma unroll
      for (int ni = 0; ni < 4; ++ni)
        bf[ni] = *(const bf16x8*)&Bs[(wn * 64 + ni * 16 + ll) * 64 + t * 32 + lg * 8];
#pragma unroll
      for (int mi = 0; mi < 4; ++mi)
#pragma unroll
        for (int ni = 0; ni < 4; ++ni)
          acc[mi][ni] = __builtin_amdgcn_mfma_f32_16x16x32_bf16(
              af[mi], bf[ni], acc[mi][ni], 0, 0, 0);
    }
    __syncthreads();
  }

#pragma unroll
  for (int mi = 0; mi < 4; ++mi)
#pragma unroll
    for (int ni = 0; ni < 4; ++ni) {
      const int col = n0 + wn * 64 + ni * 16 + ll;
      const int rowb = m0 + wm * 64 + mi * 16 + lg * 4;
#pragma unroll
      for (int r = 0; r < 4; ++r)
        o[(size_t)(rowb + r) * DMODEL + col] = acc[mi][ni][r];
    }
}

// Tile staging: 64x64 bf16 (8KB) via global_load_lds, LINEAR LDS dest with
// PRE-SWIZZLED global source (col16 ^= row&7).
#define STAGE_TILE(srcTile, srcStride, ldsT)                                  \
  {                                                                           \
    _Pragma("unroll") for (int j_ = 0; j_ < 2; ++j_) {                        \
      int slot_ = (j_ * 4 + w) * 64 + l;                                      \
      int row_ = slot_ >> 3, c16_ = slot_ & 7;                                \
      GLD_LDS16((srcTile) + (size_t)row_ * (srcStride) +                      \
                    ((c16_ ^ (row_ & 7)) << 3),                               \
                (ldsT) + (j_ * 4 + w) * 512);                                 \
    }                                                                         \
  }

// ---------------- attn pass 1: online (m, 1/l), LDS-staged K ----------------
// hb-major grid: all 32 q-tiles of one panel adjacent -> K panel L2-resident.
__global__ __launch_bounds__(256, 3)
void attn_ml(const unsigned short* __restrict__ Qp,
             const unsigned short* __restrict__ Kp,
             float2* __restrict__ mlbuf) {
  const int idx = blockIdx.x;
  const int hb = idx >> 5;                 // panel-major
  const int qt = 31 - (idx & 31);          // heavy tiles first within panel
  const int h = hb >> 1, b = hb & 1;
  const int tid = threadIdx.x, w = tid >> 6, l = tid & 63;
  const int lg = l >> 4, ll = l & 15;
  __shared__ unsigned short Kt[2][64 * 64];

  const unsigned short* kbp = Kp + (size_t)b * S_LEN * DMODEL + h * 64;
  const int q0 = qt * 64 + w * 16;
  const int nkt = qt + 1;

  bf16x8 qf[2];
  {
    const unsigned short* qb =
        Qp + (size_t)(b * S_LEN + q0 + ll) * DMODEL + h * 64 + lg * 8;
    qf[0] = *(const bf16x8*)qb;
    qf[1] = *(const bf16x8*)(qb + 32);
  }
  int rowg[4];
#pragma unroll
  for (int r = 0; r < 4; ++r) rowg[r] = q0 + lg * 4 + r;

  float m[4], lsum[4];
#pragma unroll
  for (int r = 0; r < 4; ++r) { m[r] = -1e30f; lsum[r] = 0.f; }

  STAGE_TILE(kbp + (size_t)0 * 64 * DMODEL, DMODEL, &Kt[0][0]);
  __syncthreads();

  for (int kt = 0; kt < nkt; ++kt) {
    const int cur = kt & 1;
    if (kt + 1 < nkt)
      STAGE_TILE(kbp + (size_t)(kt + 1) * 64 * DMODEL, DMODEL, &Kt[cur ^ 1][0]);
    bf16x8 kf[8];
#pragma unroll
    for (int t = 0; t < 2; ++t)
#pragma unroll
      for (int nb = 0; nb < 4; ++nb) {
        const int row = nb * 16 + ll;
        kf[t * 4 + nb] = *(const bf16x8*)&Kt[cur][row * 64 +
            (((t * 4 + lg) ^ (row & 7)) << 3)];
      }
    f32x4 sv[4];
#pragma unroll
    for (int nb = 0; nb < 4; ++nb) sv[nb] = (f32x4){0.f, 0.f, 0.f, 0.f};
#pragma unroll
    for (int t = 0; t < 2; ++t)
#pragma unroll
      for (int nb = 0; nb < 4; ++nb)
        sv[nb] = __builtin_amdgcn_mfma_f32_16x16x32_bf16(qf[t], kf[t * 4 + nb],
                                                         sv[nb], 0, 0, 0);
    if (kt == nkt - 1) {  // diagonal: causal mask
#pragma unroll
      for (int nb = 0; nb < 4; ++nb) {
        const int col = kt * 64 + nb * 16 + ll;
#pragma unroll
        for (int r = 0; r < 4; ++r)
          if (col > rowg[r]) sv[nb][r] = -1e30f;
      }
    }
#pragma unroll
    for (int r = 0; r < 4; ++r) {
      float tm = fmaxf(fmaxf(sv[0][r], sv[1][r]), fmaxf(sv[2][r], sv[3][r]));
      float mn = fmaxf(m[r], tm);
      float te = __expf(sv[0][r] - mn) + __expf(sv[1][r] - mn) +
                 __expf(sv[2][r] - mn) + __expf(sv[3][r] - mn);
      lsum[r] = lsum[r] * __expf(m[r] - mn) + te;
      m[r] = mn;
    }
    __syncthreads();
  }

#pragma unroll
  for (int off = 1; off < 16; off <<= 1)
#pragma unroll
    for (int r = 0; r < 4; ++r) {
      float om = __shfl_xor(m[r], off, 64);
      float ol = __shfl_xor(lsum[r], off, 64);
      float mn = fmaxf(m[r], om);
      lsum[r] = lsum[r] * __expf(m[r] - mn) + ol * __expf(om - mn);
      m[r] = mn;
    }

  if (ll == 0) {
    float2* mlb = mlbuf + (size_t)(b * NH + h) * S_LEN;
#pragma unroll
    for (int r = 0; r < 4; ++r)
      mlb[rowg[r]] = make_float2(m[r], 1.f / lsum[r]);
  }
}

// ---------------- attn pass 2: 32-row WGs, k-split waves, NT stores --------
// Grid: idx = hb*128 + slot*2 + qh. WG covers 32 q-rows (qt, half qh) and a
// 16-tile k-chunk; wave w owns disjoint k-tiles {ktlo+w, +4, +8, +12}.
// Halved register state (qf/cacc/sv/m) + 8KB/wave LDS -> 3 WGs/CU (12 waves)
// for latency hiding of the QK->exp->LDS->PV chain and NT store drain.
__global__ __launch_bounds__(256, 3)
void attn_p2(const unsigned short* __restrict__ Qp,
             const unsigned short* __restrict__ Kp,
             const unsigned short* __restrict__ VTp,
             const float2* __restrict__ mlbuf,
             float* __restrict__ attnw,
             float* __restrict__ ctx0,
             float* __restrict__ ctx1) {
  const int idx = blockIdx.x;
  const int hb = idx >> 7;           // panel-major ordering
  const int sl = idx & 127;
  const int slot = sl >> 1;          // (qt, ck) heavy-first mapping
  const int qh = sl & 1;             // q-half within the 64-row tile
  const int h = hb >> 1, b = hb & 1;
  int qt, ck;
  if (slot <= 16)      { ck = 0; qt = 15 + slot; }
  else if (slot == 17) { ck = 1; qt = 31; }
  else if (slot < 48)  { int u = slot - 18; int k = 15 - (u >> 1);
                         if (u & 1) { ck = 1; qt = k + 15; } else { ck = 0; qt = k - 1; } }
  else                 { ck = 1; qt = slot - 48; }

  const int ktlo = ck * 16;
  const int kthi = (qt < ktlo + 15) ? qt : (ktlo + 15);  // last value tile
  const bool hasval = (ktlo <= qt);

  const int tid = threadIdx.x, w = tid >> 6, l = tid & 63;
  const int lg = l >> 4, ll = l & 15;
  __shared__ float pf32[4][32 * 64];  // 8KB per wave (private)
  float* pfw = &pf32[w][0];

  const unsigned short* kbp = Kp + (size_t)b * S_LEN * DMODEL + h * 64;
  const unsigned short* vbp = VTp + ((size_t)(b * NH + h)) * 64 * S_LEN;
  float* pbase = attnw + ((size_t)(b * NH + h)) * S_LEN * S_LEN;
  const int q0g = qt * 64 + qh * 32;  // first of this WG's 32 rows

  if (hasval) {
    bf16x8 qf[2][2];
#pragma unroll
    for (int rb = 0; rb < 2; ++rb) {
      const unsigned short* qb =
          Qp + (size_t)(b * S_LEN + q0g + rb * 16 + ll) * DMODEL + h * 64 + lg * 8;
      qf[rb][0] = *(const bf16x8*)qb;
      qf[rb][1] = *(const bf16x8*)(qb + 32);
    }
    float m16[2][4], li16[2][4];
    {
      const float2* mlb = mlbuf + (size_t)(b * NH + h) * S_LEN;
#pragma unroll
      for (int rb = 0; rb < 2; ++rb)
#pragma unroll
        for (int r = 0; r < 4; ++r) {
          float2 t = mlb[q0g + rb * 16 + lg * 4 + r];
          m16[rb][r] = t.x;
          li16[rb][r] = t.y;
        }
    }

    f32x4 cacc[2][4];  // [q-rowblock][v-dimblock]
#pragma unroll
    for (int rb = 0; rb < 2; ++rb)
#pragma unroll
      for (int vb = 0; vb < 4; ++vb) cacc[rb][vb] = (f32x4){0.f, 0.f, 0.f, 0.f};

    for (int kt = ktlo + w; kt <= kthi; kt += 4) {
      // ---- K loads + QK for both row-blocks ----
      bf16x8 kf[2][4];  // [t][nb]
#pragma unroll
      for (int t = 0; t < 2; ++t)
#pragma unroll
        for (int nb = 0; nb < 4; ++nb)
          kf[t][nb] = *(const bf16x8*)(kbp +
              (size_t)(kt * 64 + nb * 16 + ll) * DMODEL + t * 32 + lg * 8);
      f32x4 sv[2][4];
#pragma unroll
      for (int rb = 0; rb < 2; ++rb)
#pragma unroll
        for (int nb = 0; nb < 4; ++nb) sv[rb][nb] = (f32x4){0.f, 0.f, 0.f, 0.f};
#pragma unroll
      for (int t = 0; t < 2; ++t)
#pragma unroll
        for (int rb = 0; rb < 2; ++rb)
#pragma unroll
          for (int nb = 0; nb < 4; ++nb)
            sv[rb][nb] = __builtin_amdgcn_mfma_f32_16x16x32_bf16(
                qf[rb][t], kf[t][nb], sv[rb][nb], 0, 0, 0);
      // ---- exp -> wave-private f32 LDS (32x64, swz (lg&1)<<4) ----
#pragma unroll
      for (int nb = 0; nb < 4; ++nb) {
        const int col = kt * 64 + nb * 16 + ll;
#pragma unroll
        for (int rb = 0; rb < 2; ++rb)
#pragma unroll
          for (int r = 0; r < 4; ++r) {
            const int row = q0g + rb * 16 + lg * 4 + r;
            float p = (col <= row)
                          ? __expf(sv[rb][nb][r] - m16[rb][r]) * li16[rb][r]
                          : 0.f;
            pfw[(rb * 16 + lg * 4 + r) * 64 +
                ((nb * 16 + ll) ^ ((lg & 1) << 4))] = p;
          }
      }
      // ---- PV: read P back per k-half, cvt to bf16, MFMA with V ----
#pragma unroll
      for (int t = 0; t < 2; ++t) {
        bf16x8 pfr[2];
#pragma unroll
        for (int rb = 0; rb < 2; ++rb) {
          const int row = rb * 16 + ll;
          const int c0 = (t * 32 + lg * 8) ^ (((ll >> 2) & 1) << 4);
          f32x4 lo = *(const f32x4*)&pfw[row * 64 + c0];
          f32x4 hi = *(const f32x4*)&pfw[row * 64 + c0 + 4];
          union { us4 hh2[2]; bf16x8 v; } u;
          u.hh2[0] = (us4){ f2bf(lo[0]), f2bf(lo[1]), f2bf(lo[2]), f2bf(lo[3]) };
          u.hh2[1] = (us4){ f2bf(hi[0]), f2bf(hi[1]), f2bf(hi[2]), f2bf(hi[3]) };
          pfr[rb] = u.v;
        }
        bf16x8 vf[4];
#pragma unroll
        for (int vb = 0; vb < 4; ++vb)
          vf[vb] = *(const bf16x8*)(vbp +
              (size_t)(vb * 16 + ll) * S_LEN + kt * 64 + t * 32 + lg * 8);
#pragma unroll
        for (int rb = 0; rb < 2; ++rb)
#pragma unroll
          for (int vb = 0; vb < 4; ++vb)
            cacc[rb][vb] = __builtin_amdgcn_mfma_f32_16x16x32_bf16(
                pfr[rb], vf[vb], cacc[rb][vb], 0, 0, 0);
      }
      // ---- P stores: nontemporal, 8 passes x (4 rows x 256B lines) ----
#pragma unroll
      for (int ps = 0; ps < 8; ++ps) {
        const int lrow = ps * 4 + lg;  // (lrow>>2)&1 == ps&1
        const int cb = (ll * 4) ^ ((ps & 1) << 4);
        f32x4 pv = *(const f32x4*)&pfw[lrow * 64 + cb];
        __builtin_nontemporal_store(
            pv, (f32x4*)&pbase[(size_t)(q0g + lrow) * S_LEN + kt * 64 + ll * 4]);
      }
    }

    // ---- cacc 4-way reduce across waves (the only barrier) ----
#pragma unroll
    for (int rb = 0; rb < 2; ++rb)
#pragma unroll
      for (int vb = 0; vb < 4; ++vb)
#pragma unroll
        for (int r = 0; r < 4; ++r)
          pfw[(rb * 16 + lg * 4 + r) * 64 +
              ((vb * 16 + ll) ^ ((lg & 1) << 4))] = cacc[rb][vb][r];
    __syncthreads();
    float* co = ck ? ctx1 : ctx0;
#pragma unroll
    for (int ps2 = 0; ps2 < 2; ++ps2) {
      const int lrow = w * 8 + ps2 * 4 + lg;  // (lrow>>2)&1 == ps2&1
      const int cb = (ll * 4) ^ ((ps2 & 1) << 4);
      f32x4 s0 = *(const f32x4*)&pf32[0][lrow * 64 + cb];
      f32x4 s1 = *(const f32x4*)&pf32[1][lrow * 64 + cb];
      f32x4 s2 = *(const f32x4*)&pf32[2][lrow * 64 + cb];
      f32x4 s3 = *(const f32x4*)&pf32[3][lrow * 64 + cb];
      f32x4 sm = (s0 + s1) + (s2 + s3);
      *(f32x4*)&co[(size_t)(b * S_LEN + q0g + lrow) * DMODEL + h * 64 + ll * 4] = sm;
    }
  }

  // zero-fill masked columns inside this chunk (overwrite 0xAA poison)
  // WG covers 32 rows; wave w zero-fills 8 of them.
  const int zs = ((qt + 1) * 64 > ktlo * 64) ? (qt + 1) * 64 : ktlo * 64;
  const int ze = (ktlo + 16) * 64;
  if (zs < ze) {
    f32x4 z = (f32x4){0.f, 0.f, 0.f, 0.f};
    for (int rr = 0; rr < 8; ++rr) {
      float* dst = pbase + (size_t)(q0g + w * 8 + rr) * S_LEN;
      for (int c = zs + l * 4; c < ze; c += 256)
        __builtin_nontemporal_store(z, (f32x4*)(dst + c));
    }
  }
}

extern "C" void kernel_launch(void* const* d_in, const int* in_sizes, int n_in,
                              void* d_out, int out_size, void* d_ws, size_t ws_size,
                              hipStream_t stream) {
  const float* q_in = (const float*)d_in[0];
  const float* k_in = (const float*)d_in[1];
  const float* v_in = (const float*)d_in[2];
  // d_in[3] = mask: causal triu(k=1), hardcoded in attn kernels
  const float* wq = (const float*)d_in[4];
  const float* wk = (const float*)d_in[5];
  const float* wv = (const float*)d_in[6];
  const float* wo = (const float*)d_in[7];

  const int BSD = BATCH * S_LEN * DMODEL;  // 3145728
  const int DD = DMODEL * DMODEL;          // 589824
  const int M = BATCH * S_LEN;             // 4096

  char* ws = (char*)d_ws;
  unsigned short* qbf = (unsigned short*)ws;  ws += (size_t)BSD * 2;
  unsigned short* kbf = (unsigned short*)ws;  ws += (size_t)BSD * 2;
  unsigned short* vbf = (unsigned short*)ws;  ws += (size_t)BSD * 2;
  unsigned short* wqb = (unsigned short*)ws;  ws += (size_t)DD * 2;   // contiguous
  unsigned short* wkb = (unsigned short*)ws;  ws += (size_t)DD * 2;   //  W3 =
  unsigned short* wvb = (unsigned short*)ws;  ws += (size_t)DD * 2;   //  [2304][768]
  unsigned short* wob = (unsigned short*)ws;  ws += (size_t)DD * 2;
  unsigned short* Qs  = (unsigned short*)ws;  ws += (size_t)BSD * 2;
  unsigned short* Ks  = (unsigned short*)ws;  ws += (size_t)BSD * 2;
  unsigned short* VT  = (unsigned short*)ws;  ws += (size_t)BSD * 2;
  unsigned short* ctx = (unsigned short*)ws;  ws += (size_t)BSD * 2;
  float* ctx0 = (float*)ws;                   ws += (size_t)BSD * 4;
  float* ctx1 = (float*)ws;                   ws += (size_t)BSD * 4;
  float2* mlbuf = (float2*)ws;                ws += (size_t)M * NH * sizeof(float2);
  (void)wkb; (void)wvb;

  float* out_proj = (float*)d_out;
  float* attnw = (float*)d_out + BSD;

  cvt3_kernel<<<3 * N8_BSD / 256, 256, 0, stream>>>(q_in, k_in, v_in, qbf);
  cvt4_kernel<<<4 * N8_DD / 256, 256, 0, stream>>>(wq, wk, wv, wo, wqb);

  gemm_qkv<<<dim3(M / 128, 2304 / 128), 256, 0, stream>>>(qbf, kbf, vbf, wqb,
                                                          Qs, Ks, VT);

  attn_ml<<<32 * NH * BATCH, 256, 0, stream>>>(Qs, Ks, mlbuf);
  attn_p2<<<128 * NH * BATCH, 256, 0, stream>>>(Qs, Ks, VT, mlbuf, attnw,
                                                ctx0, ctx1);
  ctx_reduce<<<BSD / 4 / 256, 256, 0, stream>>>(ctx0, ctx1, ctx);

  gemm_proj<<<dim3(M / 128, DMODEL / 128), 256, 0, stream>>>(ctx, wob, out_proj);
}